// Round 7
// baseline (5558.900 us; speedup 1.0000x reference)
//
#include <hip/hip_runtime.h>
#include <hip/hip_bf16.h>
#include <stdint.h>

typedef __hip_bfloat16 bf16;
typedef __attribute__((ext_vector_type(8))) short bf16x8;
typedef __attribute__((ext_vector_type(4))) float f32x4;

__device__ __forceinline__ float b2f(bf16 v) { return __bfloat162float(v); }
__device__ __forceinline__ bf16 f2b(float v) { return __float2bfloat16(v); }
__device__ __forceinline__ unsigned short f2bu(float v) {
    bf16 h = __float2bfloat16(v);
    return *(unsigned short*)&h;
}
__device__ __forceinline__ short f2bs(float v) {
    bf16 h = __float2bfloat16(v);
    return *(short*)&h;
}
__device__ __forceinline__ float su2f(unsigned short u) {
    unsigned int x = ((unsigned int)u) << 16;
    return *(float*)&x;
}

__device__ __forceinline__ void gload_lds16(const void* g, void* l) {
    __builtin_amdgcn_global_load_lds((const __attribute__((address_space(1))) void*)g,
                                     (__attribute__((address_space(3))) void*)l, 16, 0, 0);
}

// swizzled byte offset in [row][32 kk] bf16 tile, 80B row stride (attn tiles)
__device__ __forceinline__ int swz_byte(int row, int kk) {
    return row * 80 + 2 * (kk & 7) + 16 * ((kk >> 3) ^ (row & 3));
}

// ---------------------------------------------------------------------------
// MFMA bf16 GEMM: C[M,N] = act(A[M,K]@W[N,K]^T + bias). 128x128 tile, BK=64.
// ---------------------------------------------------------------------------
__global__ __launch_bounds__(256) void mfma_gemm(
    const bf16* __restrict__ A, const bf16* __restrict__ W,
    const float* __restrict__ bias, void* __restrict__ C,
    int M, int N, int K, int c_bf16, int relu, int store_mode)
{
    __shared__ bf16 As[128 * 64];
    __shared__ bf16 Bs[128 * 64];
    const int gx = gridDim.x;
    const int nwg = gx * gridDim.y;
    const int orig = blockIdx.y * gx + blockIdx.x;
    const int qq = nwg >> 3, rr8 = nwg & 7;
    const int xcd = orig & 7, lid = orig >> 3;
    const int wgid = (xcd < rr8 ? xcd * (qq + 1) : rr8 * (qq + 1) + (xcd - rr8) * qq) + lid;
    const int m0 = (wgid / gx) * 128, n0 = (wgid % gx) * 128;

    const int tid = threadIdx.x;
    const int wave = tid >> 6, lane = tid & 63;
    const int wr = wave >> 1, wc = wave & 1;
    const int fr = lane & 15, fg = lane >> 4;
    f32x4 acc[4][4] = {};

    const int srow = lane >> 3;
    const int sunit = (lane & 7) ^ srow;

    for (int k0 = 0; k0 < K; k0 += 64) {
#pragma unroll
        for (int c = 0; c < 4; ++c) {
            const int chunk = wave * 4 + c;
            const int arow = m0 + chunk * 8 + srow;
            const int brow = n0 + chunk * 8 + srow;
            gload_lds16(A + (size_t)arow * K + k0 + sunit * 8, (char*)As + chunk * 1024);
            gload_lds16(W + (size_t)brow * K + k0 + sunit * 8, (char*)Bs + chunk * 1024);
        }
        __syncthreads();
#pragma unroll
        for (int kk = 0; kk < 64; kk += 32) {
            bf16x8 af[4], bw[4];
            const int bo = (kk + fg * 8) * 2;
#pragma unroll
            for (int t = 0; t < 4; ++t) {
                const int ra = wr * 64 + t * 16 + fr;
                af[t] = *(const bf16x8*)((const char*)As + ra * 128 + (bo ^ ((ra & 7) << 4)));
                const int rb = wc * 64 + t * 16 + fr;
                bw[t] = *(const bf16x8*)((const char*)Bs + rb * 128 + (bo ^ ((rb & 7) << 4)));
            }
#pragma unroll
            for (int mt = 0; mt < 4; ++mt)
#pragma unroll
                for (int nt = 0; nt < 4; ++nt)
                    acc[mt][nt] = __builtin_amdgcn_mfma_f32_16x16x32_bf16(
                        af[mt], bw[nt], acc[mt][nt], 0, 0, 0);
        }
        __syncthreads();
    }
#pragma unroll
    for (int mt = 0; mt < 4; ++mt) {
#pragma unroll
        for (int r = 0; r < 4; ++r) {
            const int m = m0 + wr * 64 + mt * 16 + fg * 4 + r;
            if (m >= M) continue;
            size_t orow = (size_t)m;
            if (store_mode == 1) orow = (size_t)(m & 31) * 31 + (m >> 5);
#pragma unroll
            for (int nt = 0; nt < 4; ++nt) {
                const int n = n0 + wc * 64 + nt * 16 + fr;
                float v = acc[mt][nt][r] + bias[n];
                if (relu) v = fmaxf(v, 0.f);
                if (c_bf16) ((bf16*)C)[orow * N + n] = f2b(v);
                else        ((float*)C)[orow * N + n] = v;
            }
        }
    }
}

// ---------------------------------------------------------------------------
// Fused GEMM(N=512) + bias + residual + LayerNorm.
// out = LN(A@W^T + bias + res[row&mask]) -> xout (f32), xbout (bf16).
// Tile 128(M) x 512(N) per block, 512 threads (8 waves, 2Mx4N). M%128==0.
// ---------------------------------------------------------------------------
__global__ __launch_bounds__(512, 2) void gemm_ln(
    const bf16* __restrict__ A, const bf16* __restrict__ W,
    const float* __restrict__ bias,
    const float* __restrict__ res, int rowmask,
    const float* __restrict__ g, const float* __restrict__ b_,
    float* __restrict__ xout, bf16* __restrict__ xbout, int M, int K)
{
    __shared__ bf16 As[128 * 64];
    __shared__ bf16 Bs[512 * 64];
    __shared__ float redS[128][4];
    __shared__ float redV[128][4];

    const int tid = threadIdx.x;
    const int wave = tid >> 6, lane = tid & 63;
    const int m0 = blockIdx.x * 128;
    const int wr = wave >> 2, wc = wave & 3;
    const int fr = lane & 15, fg = lane >> 4;
    const int srow = lane >> 3;
    const int sunit = (lane & 7) ^ srow;

    f32x4 acc[4][8] = {};
    for (int k0 = 0; k0 < K; k0 += 64) {
#pragma unroll
        for (int c = 0; c < 2; ++c) {
            const int chunk = wave * 2 + c;              // 16 chunks of 8 A-rows
            const int arow = m0 + chunk * 8 + srow;
            gload_lds16(A + (size_t)arow * K + k0 + sunit * 8, (char*)As + chunk * 1024);
        }
#pragma unroll
        for (int c = 0; c < 8; ++c) {
            const int chunk = wave * 8 + c;              // 64 chunks of 8 W-rows
            const int brow = chunk * 8 + srow;
            gload_lds16(W + (size_t)brow * K + k0 + sunit * 8, (char*)Bs + chunk * 1024);
        }
        __syncthreads();
#pragma unroll
        for (int kk = 0; kk < 64; kk += 32) {
            const int bo = (kk + fg * 8) * 2;
            bf16x8 af[4];
#pragma unroll
            for (int t = 0; t < 4; ++t) {
                const int ra = wr * 64 + t * 16 + fr;
                af[t] = *(const bf16x8*)((const char*)As + ra * 128 + (bo ^ ((ra & 7) << 4)));
            }
#pragma unroll
            for (int nt = 0; nt < 8; ++nt) {
                const int rb = wc * 128 + nt * 16 + fr;
                bf16x8 bw = *(const bf16x8*)((const char*)Bs + rb * 128 + (bo ^ ((rb & 7) << 4)));
#pragma unroll
                for (int mt = 0; mt < 4; ++mt)
                    acc[mt][nt] = __builtin_amdgcn_mfma_f32_16x16x32_bf16(
                        af[mt], bw, acc[mt][nt], 0, 0, 0);
            }
        }
        __syncthreads();
    }

    float breg[8], greg[8], bbreg[8];
#pragma unroll
    for (int nt = 0; nt < 8; ++nt) {
        const int col = wc * 128 + nt * 16 + fr;
        breg[nt] = bias[col];
        greg[nt] = g[col];
        bbreg[nt] = b_[col];
    }

    // v = acc + bias (+res); accumulate per-row sum / sumsq
#pragma unroll
    for (int mt = 0; mt < 4; ++mt) {
#pragma unroll
        for (int r = 0; r < 4; ++r) {
            const int rl = wr * 64 + mt * 16 + fg * 4 + r;
            const float* rrow = res ? res + (size_t)((m0 + rl) & rowmask) * 512 : nullptr;
            float s1 = 0.f, s2 = 0.f;
#pragma unroll
            for (int nt = 0; nt < 8; ++nt) {
                float v = acc[mt][nt][r] + breg[nt];
                if (rrow) v += rrow[wc * 128 + nt * 16 + fr];
                acc[mt][nt][r] = v;
                s1 += v; s2 += v * v;
            }
            s1 += __shfl_xor(s1, 1); s2 += __shfl_xor(s2, 1);
            s1 += __shfl_xor(s1, 2); s2 += __shfl_xor(s2, 2);
            s1 += __shfl_xor(s1, 4); s2 += __shfl_xor(s2, 4);
            s1 += __shfl_xor(s1, 8); s2 += __shfl_xor(s2, 8);
            if (fr == 0) { redS[rl][wc] = s1; redV[rl][wc] = s2; }
        }
    }
    __syncthreads();

#pragma unroll
    for (int mt = 0; mt < 4; ++mt) {
#pragma unroll
        for (int r = 0; r < 4; ++r) {
            const int rl = wr * 64 + mt * 16 + fg * 4 + r;
            const float s1 = redS[rl][0] + redS[rl][1] + redS[rl][2] + redS[rl][3];
            const float s2 = redV[rl][0] + redV[rl][1] + redV[rl][2] + redV[rl][3];
            const float mean = s1 * (1.f / 512.f);
            const float var = s2 * (1.f / 512.f) - mean * mean;
            const float rstd = rsqrtf(var + 1e-5f);
            const size_t grow = (size_t)(m0 + rl);
#pragma unroll
            for (int nt = 0; nt < 8; ++nt) {
                const int col = wc * 128 + nt * 16 + fr;
                const float val = (acc[mt][nt][r] - mean) * rstd * greg[nt] + bbreg[nt];
                xout[grow * 512 + col] = val;
                xbout[grow * 512 + col] = f2b(val);
            }
        }
    }
}

// ---------------------------------------------------------------------------
// MFMA self-attention. Block = (mb, head-pair). T=32, dh=64.
// ---------------------------------------------------------------------------
__global__ __launch_bounds__(256) void self_attn_mfma(
    const bf16* __restrict__ qkv, const int* __restrict__ input_ids,
    bf16* __restrict__ attn_out)
{
    const int bid = blockIdx.x;
    const int hp = bid & 3;
    const int mb = bid >> 2;
    const int b = mb & 31;
    const size_t rowbase = (size_t)mb * 32;

    __shared__ __align__(16) char vt_raw[2][64 * 80];
    __shared__ __align__(16) char ps_raw[4][16 * 80];
    __shared__ float kpmv[32];

    const int tid = threadIdx.x;
    {
        const int r = tid & 31, u = tid >> 5;
#pragma unroll
        for (int e2 = 0; e2 < 2; ++e2) {
            const int h = hp * 2 + e2;
            bf16x8 v8 = *(const bf16x8*)(qkv + (rowbase + r) * 1536 + 1024 + h * 64 + u * 8);
#pragma unroll
            for (int j = 0; j < 8; ++j)
                *(short*)(vt_raw[e2] + swz_byte(u * 8 + j, r)) = v8[j];
        }
    }
    if (tid < 32) kpmv[tid] = (input_ids[b * 32 + tid] == 0) ? -1e9f : 0.f;
    __syncthreads();

    const int wave = tid >> 6, lane = tid & 63;
    const int e = wave >> 1;
    const int h = hp * 2 + e;
    const int qi = wave & 1;
    const int c = lane & 15, fg = lane >> 4;

    const bf16* qrow = qkv + (rowbase + qi * 16 + c) * 1536 + h * 64;
    bf16x8 af0 = *(const bf16x8*)(qrow + fg * 8);
    bf16x8 af1 = *(const bf16x8*)(qrow + 32 + fg * 8);
    f32x4 s[2];
#pragma unroll
    for (int kj = 0; kj < 2; ++kj) {
        const bf16* krow = qkv + (rowbase + kj * 16 + c) * 1536 + 512 + h * 64;
        bf16x8 b0 = *(const bf16x8*)(krow + fg * 8);
        bf16x8 b1 = *(const bf16x8*)(krow + 32 + fg * 8);
        f32x4 a = {};
        a = __builtin_amdgcn_mfma_f32_16x16x32_bf16(af0, b0, a, 0, 0, 0);
        a = __builtin_amdgcn_mfma_f32_16x16x32_bf16(af1, b1, a, 0, 0, 0);
        s[kj] = a;
    }
#pragma unroll
    for (int r = 0; r < 4; ++r) {
        const int qg = qi * 16 + fg * 4 + r;
        float v0 = s[0][r] * 0.125f + kpmv[c];
        float v1 = s[1][r] * 0.125f + kpmv[16 + c];
        if (c > qg) v0 = -1e9f;
        if (16 + c > qg) v1 = -1e9f;
        float m = fmaxf(v0, v1);
        m = fmaxf(m, __shfl_xor(m, 1)); m = fmaxf(m, __shfl_xor(m, 2));
        m = fmaxf(m, __shfl_xor(m, 4)); m = fmaxf(m, __shfl_xor(m, 8));
        float e0 = __expf(v0 - m), e1 = __expf(v1 - m);
        float sm = e0 + e1;
        sm += __shfl_xor(sm, 1); sm += __shfl_xor(sm, 2);
        sm += __shfl_xor(sm, 4); sm += __shfl_xor(sm, 8);
        float inv = 1.f / sm;
        *(short*)(ps_raw[wave] + swz_byte(fg * 4 + r, c))      = f2bs(e0 * inv);
        *(short*)(ps_raw[wave] + swz_byte(fg * 4 + r, 16 + c)) = f2bs(e1 * inv);
    }
    bf16x8 pa = *(const bf16x8*)(ps_raw[wave] + c * 80 + 16 * (fg ^ (c & 3)));
    f32x4 o[4];
#pragma unroll
    for (int dj = 0; dj < 4; ++dj) {
        bf16x8 bv = *(const bf16x8*)(vt_raw[e] + (dj * 16 + c) * 80 + 16 * (fg ^ (c & 3)));
        f32x4 a = {};
        o[dj] = __builtin_amdgcn_mfma_f32_16x16x32_bf16(pa, bv, a, 0, 0, 0);
    }
#pragma unroll
    for (int dj = 0; dj < 4; ++dj)
#pragma unroll
        for (int r = 0; r < 4; ++r)
            attn_out[(rowbase + qi * 16 + fg * 4 + r) * 512 + h * 64 + dj * 16 + c] = f2b(o[dj][r]);
}

// ---------------------------------------------------------------------------
// MFMA cross-attention reading env_kv (9216 x 1024 = k|v) via computed gather.
// mem index m = m0 + (mb_local>>5); b = mb_local&31; j in [0,32) -> env row.
// ---------------------------------------------------------------------------
__device__ __forceinline__ int env_idx(int m, int b, int j) {
    int gi = j / 9, sp = j - gi * 9;
    int t = m - 1 + gi;
    t = t < 0 ? 0 : (t > 31 ? 31 : t);
    return (b * 32 + t) * 9 + sp;
}

__global__ __launch_bounds__(256) void cross_attn_mfma(
    const bf16* __restrict__ q, int qshared, const bf16* __restrict__ ekv,
    bf16* __restrict__ attn_out, int m0glob)
{
    const int bid = blockIdx.x;
    const int hp = bid & 3;
    const int mb = bid >> 2;
    const int b = mb & 31;
    const int m = m0glob + (mb >> 5);
    const size_t qb = (size_t)(qshared ? b : mb) * 32;
    const size_t ob = (size_t)mb * 32;

    __shared__ __align__(16) char vt_raw[2][64 * 80];
    __shared__ __align__(16) char ps_raw[4][16 * 80];

    const int tid = threadIdx.x;
    {
        const int r = tid & 31, u = tid >> 5;
        const size_t erow = (size_t)env_idx(m, b, r) * 1024;
#pragma unroll
        for (int e2 = 0; e2 < 2; ++e2) {
            const int h = hp * 2 + e2;
            bf16x8 v8 = *(const bf16x8*)(ekv + erow + 512 + h * 64 + u * 8);
#pragma unroll
            for (int j = 0; j < 8; ++j)
                *(short*)(vt_raw[e2] + swz_byte(u * 8 + j, r)) = v8[j];
        }
    }
    __syncthreads();

    const int wave = tid >> 6, lane = tid & 63;
    const int e = wave >> 1;
    const int h = hp * 2 + e;
    const int qi = wave & 1;
    const int c = lane & 15, fg = lane >> 4;

    const bf16* qrow = q + (qb + qi * 16 + c) * 512 + h * 64;
    bf16x8 af0 = *(const bf16x8*)(qrow + fg * 8);
    bf16x8 af1 = *(const bf16x8*)(qrow + 32 + fg * 8);
    f32x4 s[2];
#pragma unroll
    for (int kj = 0; kj < 2; ++kj) {
        const size_t erow = (size_t)env_idx(m, b, kj * 16 + c) * 1024;
        bf16x8 b0 = *(const bf16x8*)(ekv + erow + h * 64 + fg * 8);
        bf16x8 b1 = *(const bf16x8*)(ekv + erow + h * 64 + 32 + fg * 8);
        f32x4 a = {};
        a = __builtin_amdgcn_mfma_f32_16x16x32_bf16(af0, b0, a, 0, 0, 0);
        a = __builtin_amdgcn_mfma_f32_16x16x32_bf16(af1, b1, a, 0, 0, 0);
        s[kj] = a;
    }
#pragma unroll
    for (int r = 0; r < 4; ++r) {
        float v0 = s[0][r] * 0.125f;
        float v1 = (16 + c < 27) ? s[1][r] * 0.125f : -1e9f;
        float m2 = fmaxf(v0, v1);
        m2 = fmaxf(m2, __shfl_xor(m2, 1)); m2 = fmaxf(m2, __shfl_xor(m2, 2));
        m2 = fmaxf(m2, __shfl_xor(m2, 4)); m2 = fmaxf(m2, __shfl_xor(m2, 8));
        float e0 = __expf(v0 - m2), e1 = __expf(v1 - m2);
        float sm = e0 + e1;
        sm += __shfl_xor(sm, 1); sm += __shfl_xor(sm, 2);
        sm += __shfl_xor(sm, 4); sm += __shfl_xor(sm, 8);
        float inv = 1.f / sm;
        *(short*)(ps_raw[wave] + swz_byte(fg * 4 + r, c))      = f2bs(e0 * inv);
        *(short*)(ps_raw[wave] + swz_byte(fg * 4 + r, 16 + c)) = f2bs(e1 * inv);
    }
    bf16x8 pa = *(const bf16x8*)(ps_raw[wave] + c * 80 + 16 * (fg ^ (c & 3)));
    f32x4 o[4];
#pragma unroll
    for (int dj = 0; dj < 4; ++dj) {
        bf16x8 bv = *(const bf16x8*)(vt_raw[e] + (dj * 16 + c) * 80 + 16 * (fg ^ (c & 3)));
        f32x4 a = {};
        o[dj] = __builtin_amdgcn_mfma_f32_16x16x32_bf16(pa, bv, a, 0, 0, 0);
    }
#pragma unroll
    for (int dj = 0; dj < 4; ++dj)
#pragma unroll
        for (int r = 0; r < 4; ++r)
            attn_out[(ob + qi * 16 + fg * 4 + r) * 512 + h * 64 + dj * 16 + c] = f2b(o[dj][r]);
}

// ---------------------------------------------------------------------------
// LayerNorm over D=512 (final outn); f32 in, optional f32/bf16 out.
// ---------------------------------------------------------------------------
__global__ __launch_bounds__(256) void ln_kernel(
    const float* __restrict__ x, const float* __restrict__ g,
    const float* __restrict__ b_, float* __restrict__ outf,
    bf16* __restrict__ outb, int rows)
{
    int row = blockIdx.x * 4 + (threadIdx.x >> 6);
    if (row >= rows) return;
    int lane = threadIdx.x & 63;
    const float4* xr = (const float4*)(x + (size_t)row * 512);
    float4 v[2];
    float sum = 0.f;
#pragma unroll
    for (int j = 0; j < 2; ++j) {
        v[j] = xr[lane + 64 * j];
        sum += v[j].x + v[j].y + v[j].z + v[j].w;
    }
    for (int o = 32; o; o >>= 1) sum += __shfl_xor(sum, o, 64);
    float mean = sum * (1.f / 512.f);
    float vs = 0.f;
#pragma unroll
    for (int j = 0; j < 2; ++j) {
        float dx = v[j].x - mean, dy = v[j].y - mean, dz = v[j].z - mean, dw = v[j].w - mean;
        vs += dx * dx + dy * dy + dz * dz + dw * dw;
    }
    for (int o = 32; o; o >>= 1) vs += __shfl_xor(vs, o, 64);
    float rstd = rsqrtf(vs * (1.f / 512.f) + 1e-5f);
#pragma unroll
    for (int j = 0; j < 2; ++j) {
        int u = lane + 64 * j;
        float4 g4 = ((const float4*)g)[u];
        float4 b4 = ((const float4*)b_)[u];
        float4 o4;
        o4.x = (v[j].x - mean) * rstd * g4.x + b4.x;
        o4.y = (v[j].y - mean) * rstd * g4.y + b4.y;
        o4.z = (v[j].z - mean) * rstd * g4.z + b4.z;
        o4.w = (v[j].w - mean) * rstd * g4.w + b4.w;
        if (outf) ((float4*)(outf + (size_t)row * 512))[u] = o4;
        if (outb) {
            ushort4 s4 = { f2bu(o4.x), f2bu(o4.y), f2bu(o4.z), f2bu(o4.w) };
            ((ushort4*)(outb + (size_t)row * 512))[u] = s4;
        }
    }
}

// env row build + LN -> bf16 env_b. rows = 9216.
__global__ __launch_bounds__(256) void env_ln_kernel(
    const float* __restrict__ astate, const int* __restrict__ atok,
    const float* __restrict__ emb, const int* __restrict__ goal,
    const float* __restrict__ g, const float* __restrict__ b_, bf16* __restrict__ envb)
{
    int row = blockIdx.x * 4 + (threadIdx.x >> 6);
    if (row >= 9216) return;
    int lane = threadIdx.x & 63;
    int s9 = row % 9;
    int bt = row / 9;
    float4 v[2];
    if (s9 < 8) {
        int ar = bt * 8 + s9;
        float msk = (atok[ar] != -1) ? 1.f : 0.f;
#pragma unroll
        for (int j = 0; j < 2; ++j) {
            float4 a = ((const float4*)(astate + (size_t)ar * 512))[lane + 64 * j];
            a.x *= msk; a.y *= msk; a.z *= msk; a.w *= msk;
            v[j] = a;
        }
    } else {
        int gi = goal[bt >> 5];
#pragma unroll
        for (int j = 0; j < 2; ++j)
            v[j] = ((const float4*)(emb + (size_t)gi * 512))[lane + 64 * j];
    }
    float sum = 0.f;
#pragma unroll
    for (int j = 0; j < 2; ++j) sum += v[j].x + v[j].y + v[j].z + v[j].w;
    for (int o = 32; o; o >>= 1) sum += __shfl_xor(sum, o, 64);
    float mean = sum * (1.f / 512.f);
    float vs = 0.f;
#pragma unroll
    for (int j = 0; j < 2; ++j) {
        float dx = v[j].x - mean, dy = v[j].y - mean, dz = v[j].z - mean, dw = v[j].w - mean;
        vs += dx * dx + dy * dy + dz * dz + dw * dw;
    }
    for (int o = 32; o; o >>= 1) vs += __shfl_xor(vs, o, 64);
    float rstd = rsqrtf(vs * (1.f / 512.f) + 1e-5f);
#pragma unroll
    for (int j = 0; j < 2; ++j) {
        int u = lane + 64 * j;
        float4 g4 = ((const float4*)g)[u];
        float4 b4 = ((const float4*)b_)[u];
        ushort4 s4;
        s4.x = f2bu((v[j].x - mean) * rstd * g4.x + b4.x);
        s4.y = f2bu((v[j].y - mean) * rstd * g4.y + b4.y);
        s4.z = f2bu((v[j].z - mean) * rstd * g4.z + b4.z);
        s4.w = f2bu((v[j].w - mean) * rstd * g4.w + b4.w);
        ((ushort4*)(envb + (size_t)row * 512))[u] = s4;
    }
}

__global__ void xcatb_kernel(const int* __restrict__ ids, const float* __restrict__ ego,
                             const bf16* __restrict__ emb_b, bf16* __restrict__ xcat)
{
    int row = blockIdx.x;   // 1024
    int tid = threadIdx.x;  // 128
    int b = row >> 5;
    int id = ids[row];
    bf16x8* dst = (bf16x8*)(xcat + (size_t)row * 576);
    if (tid < 64) {
        dst[tid] = ((const bf16x8*)(emb_b + (size_t)id * 512))[tid];
    } else if (tid == 64) {
        bf16x8 u = {};
        u[0] = f2bs(ego[b * 3 + 0]);
        u[1] = f2bs(ego[b * 3 + 1]);
        u[2] = f2bs(ego[b * 3 + 2]);
        dst[64] = u;
    } else if (tid < 72) {
        bf16x8 z = {};
        dst[tid] = z;
    }
}

__global__ void acatb_kernel(const int* __restrict__ atok, const float* __restrict__ afeat,
                             const bf16* __restrict__ emb_b, bf16* __restrict__ acat)
{
    int row = blockIdx.x;   // 8192
    int tid = threadIdx.x;  // 128
    int tok = atok[row];
    int id = (tok != -1) ? tok : 0;
    bf16x8* dst = (bf16x8*)(acat + (size_t)row * 576);
    if (tid < 64) {
        dst[tid] = ((const bf16x8*)(emb_b + (size_t)id * 512))[tid];
    } else if (tid == 64) {
        bf16x8 u = {};
#pragma unroll
        for (int e = 0; e < 5; ++e) u[e] = f2bs(afeat[(size_t)row * 5 + e]);
        dst[64] = u;
    } else if (tid < 72) {
        bf16x8 z = {};
        dst[tid] = z;
    }
}

__global__ void sel_kernel(const float* __restrict__ x, float* __restrict__ sel, int m0, int cm)
{
    int row = blockIdx.x;   // cm*32
    int ml = row >> 5, b = row & 31;
    int m = m0 + ml;
    const float4* src = (const float4*)(x + ((size_t)(ml * 32 + b) * 32 + (m + 1)) * 512);
    float4* dst = (float4*)(sel + ((size_t)m * 32 + b) * 512);
    dst[threadIdx.x] = src[threadIdx.x];
}

__global__ void fill_kernel(float* __restrict__ o, int n, float v)
{
    int i = blockIdx.x * 256 + threadIdx.x;
    if (i < n) o[i] = v;
}

__global__ void cvtw_kernel(const float* __restrict__ s, unsigned short* __restrict__ d, int n)
{
    int n4 = n >> 2;
    int stride = gridDim.x * blockDim.x;
    for (int i = blockIdx.x * blockDim.x + threadIdx.x; i < n4; i += stride) {
        float4 v = ((const float4*)s)[i];
        ushort4 u = { f2bu(v.x), f2bu(v.y), f2bu(v.z), f2bu(v.w) };
        ((ushort4*)d)[i] = u;
    }
}

__global__ void cvtpad_kernel(const float* __restrict__ s, bf16* __restrict__ d, int Ks)
{
    int row = blockIdx.x;
    int tid = threadIdx.x;
    for (int c = tid; c < 576; c += 256) {
        float v = (c < Ks) ? s[(size_t)row * Ks + c] : 0.f;
        d[(size_t)row * 576 + c] = f2b(v);
    }
}

// ---------------------------------------------------------------------------
extern "C" void kernel_launch(void* const* d_in, const int* in_sizes, int n_in,
                              void* d_out, int out_size, void* d_ws, size_t ws_size,
                              hipStream_t stream)
{
    float* out = (float*)d_out;
    if (n_in < 40) {
        fill_kernel<<<(out_size + 255) / 256, 256, 0, stream>>>(out, out_size, 1e6f);
        return;
    }
    const int*   input_ids = (const int*)d_in[0];
    const float* ego       = (const float*)d_in[1];
    const int*   atok      = (const int*)d_in[2];
    const float* afeat     = (const float*)d_in[3];
    const int*   goal      = (const int*)d_in[4];
    const float* emb       = (const float*)d_in[5];
    const float* se_w1 = (const float*)d_in[6];
    const float* se_b1 = (const float*)d_in[7];
    const float* se_w2 = (const float*)d_in[8];
    const float* se_b2 = (const float*)d_in[9];
    const float* be_w1 = (const float*)d_in[10];
    const float* be_b1 = (const float*)d_in[11];
    const float* be_w2 = (const float*)d_in[12];
    const float* be_b2 = (const float*)d_in[13];
    const float* in_g  = (const float*)d_in[14];
    const float* in_b  = (const float*)d_in[15];
    const float* mem_g = (const float*)d_in[16];
    const float* mem_b = (const float*)d_in[17];
    const float* outn_g = (const float*)d_in[18];
    const float* outn_b = (const float*)d_in[19];
    const float* sa_in_w  = (const float*)d_in[20];
    const float* sa_in_b  = (const float*)d_in[21];
    const float* sa_out_w = (const float*)d_in[22];
    const float* sa_out_b = (const float*)d_in[23];
    const float* ca_in_w  = (const float*)d_in[24];
    const float* ca_in_b  = (const float*)d_in[25];
    const float* ca_out_w = (const float*)d_in[26];
    const float* ca_out_b = (const float*)d_in[27];
    const float* ff_w1 = (const float*)d_in[28];
    const float* ff_b1 = (const float*)d_in[29];
    const float* ff_w2 = (const float*)d_in[30];
    const float* ff_b2 = (const float*)d_in[31];
    const float* ln1_g = (const float*)d_in[32];
    const float* ln1_b = (const float*)d_in[33];
    const float* ln2_g = (const float*)d_in[34];
    const float* ln2_b = (const float*)d_in[35];
    const float* ln3_g = (const float*)d_in[36];
    const float* ln3_b = (const float*)d_in[37];
    const float* proj_w = (const float*)d_in[38];
    const float* proj_b = (const float*)d_in[39];

    auto ALIGN = [](size_t b) { return (b + 255) & ~(size_t)255; };
    uintptr_t base = (uintptr_t)d_ws;
    uintptr_t cur = (base + 255) & ~(uintptr_t)255;
    auto alloc = [&](size_t bytes) -> char* {
        char* r = (char*)cur; cur += (bytes + 255) & ~(size_t)255; return r;
    };

    // ---------------- persistent allocations ----------------
    float* self_state = (float*)alloc((size_t)1024 * 512 * 4);
    bf16*  ss_b       = (bf16*) alloc((size_t)1024 * 512 * 2);
    float* x0         = (float*)alloc((size_t)1024 * 512 * 4);
    bf16*  xb0        = (bf16*) alloc((size_t)1024 * 512 * 2);
    bf16*  q0b        = (bf16*) alloc((size_t)1024 * 512 * 2);
    bf16*  qkv0       = (bf16*) alloc((size_t)1024 * 1536 * 2);
    bf16*  araw0      = (bf16*) alloc((size_t)1024 * 512 * 2);
    bf16*  env_b      = (bf16*) alloc((size_t)9216 * 512 * 2);
    bf16*  env_kv     = (bf16*) alloc((size_t)4 * 9216 * 1024 * 2);
    float* sel        = (float*)alloc((size_t)1024 * 512 * 4);
    bf16*  sel_ln_b   = (bf16*) alloc((size_t)1024 * 512 * 2);
    // bf16 weights
    bf16* w_emb   = (bf16*)alloc((size_t)4096 * 512 * 2);
    bf16* w_se1p  = (bf16*)alloc((size_t)512 * 576 * 2);
    bf16* w_be1p  = (bf16*)alloc((size_t)512 * 576 * 2);
    bf16* w_se2   = (bf16*)alloc((size_t)512 * 512 * 2);
    bf16* w_be2   = (bf16*)alloc((size_t)512 * 512 * 2);
    bf16* w_sain  = (bf16*)alloc((size_t)4 * 1536 * 512 * 2);
    bf16* w_saout = (bf16*)alloc((size_t)4 * 512 * 512 * 2);
    bf16* w_cain  = (bf16*)alloc((size_t)4 * 1536 * 512 * 2);
    bf16* w_caout = (bf16*)alloc((size_t)4 * 512 * 512 * 2);
    bf16* w_ff1   = (bf16*)alloc((size_t)4 * 2048 * 512 * 2);
    bf16* w_ff2   = (bf16*)alloc((size_t)4 * 2048 * 512 * 2);
    bf16* w_proj  = (bf16*)alloc((size_t)4096 * 512 * 2);
    uintptr_t big = cur;

    size_t setup_need =
        ALIGN((size_t)1024 * 576 * 2) + ALIGN((size_t)1024 * 512 * 2) +
        ALIGN((size_t)8192 * 576 * 2) + ALIGN((size_t)8192 * 512 * 2) +
        ALIGN((size_t)8192 * 512 * 4);
    auto chunk_need = [&](int c) -> size_t {
        return ALIGN((size_t)c * 1024 * 512 * 4)      // x f32
             + ALIGN((size_t)c * 1024 * 512 * 2)      // xb
             + ALIGN((size_t)c * 1024 * 1536 * 2)     // qkv / q
             + ALIGN((size_t)c * 1024 * 512 * 2)      // araw
             + ALIGN((size_t)c * 1024 * 2048 * 2);    // ff1
    };
    int CH = 0;
    if (ws_size > (size_t)(big - base) + 4096) {
        size_t avail = ws_size - (size_t)(big - base) - 4096;
        for (int c = 31; c >= 1; --c)
            if (setup_need <= avail && chunk_need(c) <= avail) { CH = c; break; }
    }
    if (!CH) {
        fill_kernel<<<(out_size + 255) / 256, 256, 0, stream>>>(out, out_size, 1e6f);
        return;
    }

    // ---------------- weight conversion ----------------
    auto cvt = [&](const float* s, bf16* d, size_t n) {
        int n4 = (int)(n >> 2);
        int blocks = (n4 + 255) / 256; if (blocks > 2048) blocks = 2048;
        cvtw_kernel<<<blocks, 256, 0, stream>>>(s, (unsigned short*)d, (int)n);
    };
    cvt(emb, w_emb, (size_t)4096 * 512);
    cvtpad_kernel<<<512, 256, 0, stream>>>(se_w1, w_se1p, 515);
    cvtpad_kernel<<<512, 256, 0, stream>>>(be_w1, w_be1p, 517);
    cvt(se_w2, w_se2, (size_t)512 * 512);
    cvt(be_w2, w_be2, (size_t)512 * 512);
    cvt(sa_in_w, w_sain, (size_t)4 * 1536 * 512);
    cvt(sa_out_w, w_saout, (size_t)4 * 512 * 512);
    cvt(ca_in_w, w_cain, (size_t)4 * 1536 * 512);
    cvt(ca_out_w, w_caout, (size_t)4 * 512 * 512);
    cvt(ff_w1, w_ff1, (size_t)4 * 2048 * 512);
    cvt(ff_w2, w_ff2, (size_t)4 * 2048 * 512);
    cvt(proj_w, w_proj, (size_t)4096 * 512);

    auto launch_mfma = [&](const bf16* A, const bf16* W, const float* bias,
                           void* C, int c_bf16, int M, int N, int K, int relu, int smode) {
        dim3 g(N / 128, (M + 127) / 128);
        mfma_gemm<<<g, 256, 0, stream>>>(A, W, bias, C, M, N, K, c_bf16, relu, smode);
    };
    auto launch_gemm_ln = [&](const bf16* A, const bf16* W, const float* bias,
                              const float* res, int rowmask, const float* g, const float* b_,
                              float* xout, bf16* xbout, int M, int K) {
        gemm_ln<<<M / 128, 512, 0, stream>>>(A, W, bias, res, rowmask, g, b_, xout, xbout, M, K);
    };

    // ---------------- setup: encoders, env, env_kv ----------------
    {
        uintptr_t sp = big;
        auto salloc = [&](size_t b) -> char* { char* r = (char*)sp; sp += ALIGN(b); return r; };
        bf16*  xcat_b = (bf16*) salloc((size_t)1024 * 576 * 2);
        bf16*  h1b    = (bf16*) salloc((size_t)1024 * 512 * 2);
        bf16*  acat_b = (bf16*) salloc((size_t)8192 * 576 * 2);
        bf16*  ah1b   = (bf16*) salloc((size_t)8192 * 512 * 2);
        float* astate = (float*)salloc((size_t)8192 * 512 * 4);

        xcatb_kernel<<<1024, 128, 0, stream>>>(input_ids, ego, w_emb, xcat_b);
        launch_mfma(xcat_b, w_se1p, se_b1, h1b, 1, 1024, 512, 576, 1, 0);
        launch_gemm_ln(h1b, w_se2, se_b2, nullptr, 0, in_g, in_b, self_state, ss_b, 1024, 512);

        acatb_kernel<<<8192, 128, 0, stream>>>(atok, afeat, w_emb, acat_b);
        launch_mfma(acat_b, w_be1p, be_b1, ah1b, 1, 8192, 512, 576, 1, 0);
        launch_mfma(ah1b, w_be2, be_b2, astate, 0, 8192, 512, 512, 0, 0);
        env_ln_kernel<<<2304, 256, 0, stream>>>(astate, atok, emb, goal, mem_g, mem_b, env_b);
    }
    // env_kv[l] = env_b @ Wkv_l (9216 x 1024), hoisted out of the chunk loop
    for (int l = 0; l < 4; ++l)
        launch_mfma(env_b, w_cain + (size_t)l * 1536 * 512 + (size_t)512 * 512,
                    ca_in_b + l * 1536 + 512,
                    env_kv + (size_t)l * 9216 * 1024, 1, 9216, 1024, 512, 0, 0);

    // ---------------- layer-0 shared prefix ----------------
    launch_mfma(ss_b, w_sain, sa_in_b, qkv0, 1, 1024, 1536, 512, 0, 0);
    self_attn_mfma<<<32 * 4, 256, 0, stream>>>(qkv0, input_ids, araw0);
    launch_gemm_ln(araw0, w_saout, sa_out_b, self_state, 0x7fffffff,
                   ln1_g, ln1_b, x0, xb0, 1024, 512);
    launch_mfma(xb0, w_cain, ca_in_b, q0b, 1, 1024, 512, 512, 0, 0);

    // ---------------- decode ----------------
    {
        uintptr_t sp = big;
        auto salloc = [&](size_t b) -> char* { char* r = (char*)sp; sp += ALIGN(b); return r; };
        float* x     = (float*)salloc((size_t)CH * 1024 * 512 * 4);
        bf16*  xb    = (bf16*) salloc((size_t)CH * 1024 * 512 * 2);
        bf16*  qkv   = (bf16*) salloc((size_t)CH * 1024 * 1536 * 2);
        bf16*  araw  = (bf16*) salloc((size_t)CH * 1024 * 512 * 2);
        bf16*  ff1b  = (bf16*) salloc((size_t)CH * 1024 * 2048 * 2);

        for (int m0 = 0; m0 < 31; m0 += CH) {
            int cm = (31 - m0) < CH ? (31 - m0) : CH;
            int Mr = cm * 1024;
            // --- layer 0 (shared self-attn prefix + shared q precomputed) ---
            cross_attn_mfma<<<cm * 32 * 4, 256, 0, stream>>>(q0b, 1, env_kv, araw, m0);
            launch_gemm_ln(araw, w_caout, ca_out_b, x0, 1023, ln2_g, ln2_b, x, xb, Mr, 512);
            launch_mfma(xb, w_ff1, ff_b1, ff1b, 1, Mr, 2048, 512, 1, 0);
            launch_gemm_ln(ff1b, w_ff2, ff_b2, x, 0x7fffffff, ln3_g, ln3_b, x, xb, Mr, 2048);
            // --- layers 1..3 ---
            for (int l = 1; l < 4; ++l) {
                launch_mfma(xb, w_sain + (size_t)l * 1536 * 512, sa_in_b + l * 1536,
                            qkv, 1, Mr, 1536, 512, 0, 0);
                self_attn_mfma<<<cm * 32 * 4, 256, 0, stream>>>(qkv, input_ids, araw);
                launch_gemm_ln(araw, w_saout + (size_t)l * 512 * 512, sa_out_b + l * 512,
                               x, 0x7fffffff, ln1_g + l * 512, ln1_b + l * 512, x, xb, Mr, 512);
                launch_mfma(xb, w_cain + (size_t)l * 1536 * 512, ca_in_b + l * 1536,
                            qkv, 1, Mr, 512, 512, 0, 0);
                cross_attn_mfma<<<cm * 32 * 4, 256, 0, stream>>>(
                    qkv, 0, env_kv + (size_t)l * 9216 * 1024, araw, m0);
                launch_gemm_ln(araw, w_caout + (size_t)l * 512 * 512, ca_out_b + l * 512,
                               x, 0x7fffffff, ln2_g + l * 512, ln2_b + l * 512, x, xb, Mr, 512);
                launch_mfma(xb, w_ff1 + (size_t)l * 2048 * 512, ff_b1 + l * 2048,
                            ff1b, 1, Mr, 2048, 512, 1, 0);
                launch_gemm_ln(ff1b, w_ff2 + (size_t)l * 512 * 2048, ff_b2 + l * 512,
                               x, 0x7fffffff, ln3_g + l * 512, ln3_b + l * 512, x, xb, Mr, 2048);
            }
            sel_kernel<<<cm * 32, 128, 0, stream>>>(x, sel, m0, cm);
        }
    }

    // ---------------- final: LN + vocab projection (transposed store) ----------------
    ln_kernel<<<248, 256, 0, stream>>>(sel, outn_g, outn_b, (float*)nullptr, sel_ln_b, 992);
    launch_mfma(sel_ln_b, w_proj, proj_b, out, 0, 992, 4096, 512, 0, 1);
}

// Round 9
// 3823.178 us; speedup vs baseline: 1.4540x; 1.4540x over previous
//
#include <hip/hip_runtime.h>
#include <hip/hip_bf16.h>
#include <stdint.h>

typedef __hip_bfloat16 bf16;
typedef __attribute__((ext_vector_type(8))) short bf16x8;
typedef __attribute__((ext_vector_type(4))) float f32x4;

__device__ __forceinline__ float b2f(bf16 v) { return __bfloat162float(v); }
__device__ __forceinline__ bf16 f2b(float v) { return __float2bfloat16(v); }
__device__ __forceinline__ unsigned short f2bu(float v) {
    bf16 h = __float2bfloat16(v);
    return *(unsigned short*)&h;
}
__device__ __forceinline__ short f2bs(float v) {
    bf16 h = __float2bfloat16(v);
    return *(short*)&h;
}
__device__ __forceinline__ float su2f(unsigned short u) {
    unsigned int x = ((unsigned int)u) << 16;
    return *(float*)&x;
}

__device__ __forceinline__ void gload_lds16(const void* g, void* l) {
    __builtin_amdgcn_global_load_lds((const __attribute__((address_space(1))) void*)g,
                                     (__attribute__((address_space(3))) void*)l, 16, 0, 0);
}

// swizzled byte offset in [row][32 kk] bf16 tile, 80B row stride (attn tiles)
__device__ __forceinline__ int swz_byte(int row, int kk) {
    return row * 80 + 2 * (kk & 7) + 16 * ((kk >> 3) ^ (row & 3));
}

// ---------------------------------------------------------------------------
// MFMA bf16 GEMM: C[M,N] = act(A[M,K]@W[N,K]^T + bias). 128x128 tile, BK=64.
// 992+ block grids give ~4 blocks/CU -> cross-block wave overlap hides
// barrier drains (this is why the fused 1-block/CU gemm_ln regressed).
// ---------------------------------------------------------------------------
__global__ __launch_bounds__(256) void mfma_gemm(
    const bf16* __restrict__ A, const bf16* __restrict__ W,
    const float* __restrict__ bias, void* __restrict__ C,
    int M, int N, int K, int c_bf16, int relu, int store_mode)
{
    __shared__ bf16 As[128 * 64];
    __shared__ bf16 Bs[128 * 64];
    const int gx = gridDim.x;
    const int nwg = gx * gridDim.y;
    const int orig = blockIdx.y * gx + blockIdx.x;
    const int qq = nwg >> 3, rr8 = nwg & 7;
    const int xcd = orig & 7, lid = orig >> 3;
    const int wgid = (xcd < rr8 ? xcd * (qq + 1) : rr8 * (qq + 1) + (xcd - rr8) * qq) + lid;
    const int m0 = (wgid / gx) * 128, n0 = (wgid % gx) * 128;

    const int tid = threadIdx.x;
    const int wave = tid >> 6, lane = tid & 63;
    const int wr = wave >> 1, wc = wave & 1;
    const int fr = lane & 15, fg = lane >> 4;
    f32x4 acc[4][4] = {};

    const int srow = lane >> 3;
    const int sunit = (lane & 7) ^ srow;

    for (int k0 = 0; k0 < K; k0 += 64) {
#pragma unroll
        for (int c = 0; c < 4; ++c) {
            const int chunk = wave * 4 + c;
            const int arow = m0 + chunk * 8 + srow;
            const int brow = n0 + chunk * 8 + srow;
            gload_lds16(A + (size_t)arow * K + k0 + sunit * 8, (char*)As + chunk * 1024);
            gload_lds16(W + (size_t)brow * K + k0 + sunit * 8, (char*)Bs + chunk * 1024);
        }
        __syncthreads();
#pragma unroll
        for (int kk = 0; kk < 64; kk += 32) {
            bf16x8 af[4], bw[4];
            const int bo = (kk + fg * 8) * 2;
#pragma unroll
            for (int t = 0; t < 4; ++t) {
                const int ra = wr * 64 + t * 16 + fr;
                af[t] = *(const bf16x8*)((const char*)As + ra * 128 + (bo ^ ((ra & 7) << 4)));
                const int rb = wc * 64 + t * 16 + fr;
                bw[t] = *(const bf16x8*)((const char*)Bs + rb * 128 + (bo ^ ((rb & 7) << 4)));
            }
#pragma unroll
            for (int mt = 0; mt < 4; ++mt)
#pragma unroll
                for (int nt = 0; nt < 4; ++nt)
                    acc[mt][nt] = __builtin_amdgcn_mfma_f32_16x16x32_bf16(
                        af[mt], bw[nt], acc[mt][nt], 0, 0, 0);
        }
        __syncthreads();
    }
#pragma unroll
    for (int mt = 0; mt < 4; ++mt) {
#pragma unroll
        for (int r = 0; r < 4; ++r) {
            const int m = m0 + wr * 64 + mt * 16 + fg * 4 + r;
            if (m >= M) continue;
            size_t orow = (size_t)m;
            if (store_mode == 1) orow = (size_t)(m & 31) * 31 + (m >> 5);
#pragma unroll
            for (int nt = 0; nt < 4; ++nt) {
                const int n = n0 + wc * 64 + nt * 16 + fr;
                float v = acc[mt][nt][r] + bias[n];
                if (relu) v = fmaxf(v, 0.f);
                if (c_bf16) ((bf16*)C)[orow * N + n] = f2b(v);
                else        ((float*)C)[orow * N + n] = v;
            }
        }
    }
}

// ---------------------------------------------------------------------------
// MFMA self-attention. Block = (mb, head-pair). T=32, dh=64.
// ---------------------------------------------------------------------------
__global__ __launch_bounds__(256) void self_attn_mfma(
    const bf16* __restrict__ qkv, const int* __restrict__ input_ids,
    bf16* __restrict__ attn_out)
{
    const int bid = blockIdx.x;
    const int hp = bid & 3;
    const int mb = bid >> 2;
    const int b = mb & 31;
    const size_t rowbase = (size_t)mb * 32;

    __shared__ __align__(16) char vt_raw[2][64 * 80];
    __shared__ __align__(16) char ps_raw[4][16 * 80];
    __shared__ float kpmv[32];

    const int tid = threadIdx.x;
    {
        const int r = tid & 31, u = tid >> 5;
#pragma unroll
        for (int e2 = 0; e2 < 2; ++e2) {
            const int h = hp * 2 + e2;
            bf16x8 v8 = *(const bf16x8*)(qkv + (rowbase + r) * 1536 + 1024 + h * 64 + u * 8);
#pragma unroll
            for (int j = 0; j < 8; ++j)
                *(short*)(vt_raw[e2] + swz_byte(u * 8 + j, r)) = v8[j];
        }
    }
    if (tid < 32) kpmv[tid] = (input_ids[b * 32 + tid] == 0) ? -1e9f : 0.f;
    __syncthreads();

    const int wave = tid >> 6, lane = tid & 63;
    const int e = wave >> 1;
    const int h = hp * 2 + e;
    const int qi = wave & 1;
    const int c = lane & 15, fg = lane >> 4;

    const bf16* qrow = qkv + (rowbase + qi * 16 + c) * 1536 + h * 64;
    bf16x8 af0 = *(const bf16x8*)(qrow + fg * 8);
    bf16x8 af1 = *(const bf16x8*)(qrow + 32 + fg * 8);
    f32x4 s[2];
#pragma unroll
    for (int kj = 0; kj < 2; ++kj) {
        const bf16* krow = qkv + (rowbase + kj * 16 + c) * 1536 + 512 + h * 64;
        bf16x8 b0 = *(const bf16x8*)(krow + fg * 8);
        bf16x8 b1 = *(const bf16x8*)(krow + 32 + fg * 8);
        f32x4 a = {};
        a = __builtin_amdgcn_mfma_f32_16x16x32_bf16(af0, b0, a, 0, 0, 0);
        a = __builtin_amdgcn_mfma_f32_16x16x32_bf16(af1, b1, a, 0, 0, 0);
        s[kj] = a;
    }
#pragma unroll
    for (int r = 0; r < 4; ++r) {
        const int qg = qi * 16 + fg * 4 + r;
        float v0 = s[0][r] * 0.125f + kpmv[c];
        float v1 = s[1][r] * 0.125f + kpmv[16 + c];
        if (c > qg) v0 = -1e9f;
        if (16 + c > qg) v1 = -1e9f;
        float m = fmaxf(v0, v1);
        m = fmaxf(m, __shfl_xor(m, 1)); m = fmaxf(m, __shfl_xor(m, 2));
        m = fmaxf(m, __shfl_xor(m, 4)); m = fmaxf(m, __shfl_xor(m, 8));
        float e0 = __expf(v0 - m), e1 = __expf(v1 - m);
        float sm = e0 + e1;
        sm += __shfl_xor(sm, 1); sm += __shfl_xor(sm, 2);
        sm += __shfl_xor(sm, 4); sm += __shfl_xor(sm, 8);
        float inv = 1.f / sm;
        *(short*)(ps_raw[wave] + swz_byte(fg * 4 + r, c))      = f2bs(e0 * inv);
        *(short*)(ps_raw[wave] + swz_byte(fg * 4 + r, 16 + c)) = f2bs(e1 * inv);
    }
    bf16x8 pa = *(const bf16x8*)(ps_raw[wave] + c * 80 + 16 * (fg ^ (c & 3)));
    f32x4 o[4];
#pragma unroll
    for (int dj = 0; dj < 4; ++dj) {
        bf16x8 bv = *(const bf16x8*)(vt_raw[e] + (dj * 16 + c) * 80 + 16 * (fg ^ (c & 3)));
        f32x4 a = {};
        o[dj] = __builtin_amdgcn_mfma_f32_16x16x32_bf16(pa, bv, a, 0, 0, 0);
    }
#pragma unroll
    for (int dj = 0; dj < 4; ++dj)
#pragma unroll
        for (int r = 0; r < 4; ++r)
            attn_out[(rowbase + qi * 16 + fg * 4 + r) * 512 + h * 64 + dj * 16 + c] = f2b(o[dj][r]);
}

// ---------------------------------------------------------------------------
// MFMA cross-attention reading env_kv (9216 x 1024 = k|v) via computed gather.
// ---------------------------------------------------------------------------
__device__ __forceinline__ int env_idx(int m, int b, int j) {
    int gi = j / 9, sp = j - gi * 9;
    int t = m - 1 + gi;
    t = t < 0 ? 0 : (t > 31 ? 31 : t);
    return (b * 32 + t) * 9 + sp;
}

__global__ __launch_bounds__(256) void cross_attn_mfma(
    const bf16* __restrict__ q, int qshared, const bf16* __restrict__ ekv,
    bf16* __restrict__ attn_out, int m0glob)
{
    const int bid = blockIdx.x;
    const int hp = bid & 3;
    const int mb = bid >> 2;
    const int b = mb & 31;
    const int m = m0glob + (mb >> 5);
    const size_t qb = (size_t)(qshared ? b : mb) * 32;
    const size_t ob = (size_t)mb * 32;

    __shared__ __align__(16) char vt_raw[2][64 * 80];
    __shared__ __align__(16) char ps_raw[4][16 * 80];

    const int tid = threadIdx.x;
    {
        const int r = tid & 31, u = tid >> 5;
        const size_t erow = (size_t)env_idx(m, b, r) * 1024;
#pragma unroll
        for (int e2 = 0; e2 < 2; ++e2) {
            const int h = hp * 2 + e2;
            bf16x8 v8 = *(const bf16x8*)(ekv + erow + 512 + h * 64 + u * 8);
#pragma unroll
            for (int j = 0; j < 8; ++j)
                *(short*)(vt_raw[e2] + swz_byte(u * 8 + j, r)) = v8[j];
        }
    }
    __syncthreads();

    const int wave = tid >> 6, lane = tid & 63;
    const int e = wave >> 1;
    const int h = hp * 2 + e;
    const int qi = wave & 1;
    const int c = lane & 15, fg = lane >> 4;

    const bf16* qrow = q + (qb + qi * 16 + c) * 512 + h * 64;
    bf16x8 af0 = *(const bf16x8*)(qrow + fg * 8);
    bf16x8 af1 = *(const bf16x8*)(qrow + 32 + fg * 8);
    f32x4 s[2];
#pragma unroll
    for (int kj = 0; kj < 2; ++kj) {
        const size_t erow = (size_t)env_idx(m, b, kj * 16 + c) * 1024;
        bf16x8 b0 = *(const bf16x8*)(ekv + erow + h * 64 + fg * 8);
        bf16x8 b1 = *(const bf16x8*)(ekv + erow + h * 64 + 32 + fg * 8);
        f32x4 a = {};
        a = __builtin_amdgcn_mfma_f32_16x16x32_bf16(af0, b0, a, 0, 0, 0);
        a = __builtin_amdgcn_mfma_f32_16x16x32_bf16(af1, b1, a, 0, 0, 0);
        s[kj] = a;
    }
#pragma unroll
    for (int r = 0; r < 4; ++r) {
        float v0 = s[0][r] * 0.125f;
        float v1 = (16 + c < 27) ? s[1][r] * 0.125f : -1e9f;
        float m2 = fmaxf(v0, v1);
        m2 = fmaxf(m2, __shfl_xor(m2, 1)); m2 = fmaxf(m2, __shfl_xor(m2, 2));
        m2 = fmaxf(m2, __shfl_xor(m2, 4)); m2 = fmaxf(m2, __shfl_xor(m2, 8));
        float e0 = __expf(v0 - m2), e1 = __expf(v1 - m2);
        float sm = e0 + e1;
        sm += __shfl_xor(sm, 1); sm += __shfl_xor(sm, 2);
        sm += __shfl_xor(sm, 4); sm += __shfl_xor(sm, 8);
        float inv = 1.f / sm;
        *(short*)(ps_raw[wave] + swz_byte(fg * 4 + r, c))      = f2bs(e0 * inv);
        *(short*)(ps_raw[wave] + swz_byte(fg * 4 + r, 16 + c)) = f2bs(e1 * inv);
    }
    bf16x8 pa = *(const bf16x8*)(ps_raw[wave] + c * 80 + 16 * (fg ^ (c & 3)));
    f32x4 o[4];
#pragma unroll
    for (int dj = 0; dj < 4; ++dj) {
        bf16x8 bv = *(const bf16x8*)(vt_raw[e] + (dj * 16 + c) * 80 + 16 * (fg ^ (c & 3)));
        f32x4 a = {};
        o[dj] = __builtin_amdgcn_mfma_f32_16x16x32_bf16(pa, bv, a, 0, 0, 0);
    }
#pragma unroll
    for (int dj = 0; dj < 4; ++dj)
#pragma unroll
        for (int r = 0; r < 4; ++r)
            attn_out[(ob + qi * 16 + fg * 4 + r) * 512 + h * 64 + dj * 16 + c] = f2b(o[dj][r]);
}

// ---------------------------------------------------------------------------
// LayerNorm over D=512; f32 in, optional f32/bf16 out.
// ---------------------------------------------------------------------------
__global__ __launch_bounds__(256) void ln_kernel(
    const float* __restrict__ x, const float* __restrict__ g,
    const float* __restrict__ b_, float* __restrict__ outf,
    bf16* __restrict__ outb, int rows)
{
    int row = blockIdx.x * 4 + (threadIdx.x >> 6);
    if (row >= rows) return;
    int lane = threadIdx.x & 63;
    const float4* xr = (const float4*)(x + (size_t)row * 512);
    float4 v[2];
    float sum = 0.f;
#pragma unroll
    for (int j = 0; j < 2; ++j) {
        v[j] = xr[lane + 64 * j];
        sum += v[j].x + v[j].y + v[j].z + v[j].w;
    }
    for (int o = 32; o; o >>= 1) sum += __shfl_xor(sum, o, 64);
    float mean = sum * (1.f / 512.f);
    float vs = 0.f;
#pragma unroll
    for (int j = 0; j < 2; ++j) {
        float dx = v[j].x - mean, dy = v[j].y - mean, dz = v[j].z - mean, dw = v[j].w - mean;
        vs += dx * dx + dy * dy + dz * dz + dw * dw;
    }
    for (int o = 32; o; o >>= 1) vs += __shfl_xor(vs, o, 64);
    float rstd = rsqrtf(vs * (1.f / 512.f) + 1e-5f);
#pragma unroll
    for (int j = 0; j < 2; ++j) {
        int u = lane + 64 * j;
        float4 g4 = ((const float4*)g)[u];
        float4 b4 = ((const float4*)b_)[u];
        float4 o4;
        o4.x = (v[j].x - mean) * rstd * g4.x + b4.x;
        o4.y = (v[j].y - mean) * rstd * g4.y + b4.y;
        o4.z = (v[j].z - mean) * rstd * g4.z + b4.z;
        o4.w = (v[j].w - mean) * rstd * g4.w + b4.w;
        if (outf) ((float4*)(outf + (size_t)row * 512))[u] = o4;
        if (outb) {
            ushort4 s4 = { f2bu(o4.x), f2bu(o4.y), f2bu(o4.z), f2bu(o4.w) };
            ((ushort4*)(outb + (size_t)row * 512))[u] = s4;
        }
    }
}

// xout = LN(xin[row&mask] + br[row]); writes f32 xout and bf16 xbout.
__global__ __launch_bounds__(256) void ln_res2_kernel(
    const float* __restrict__ xin, int rowmask, const bf16* __restrict__ br,
    const float* __restrict__ g, const float* __restrict__ b_,
    float* __restrict__ xout, bf16* __restrict__ xbout, int rows)
{
    int row = blockIdx.x * 4 + (threadIdx.x >> 6);
    if (row >= rows) return;
    int lane = threadIdx.x & 63;
    const float4* xr = (const float4*)(xin + (size_t)(row & rowmask) * 512);
    const ushort4* brr = (const ushort4*)(br + (size_t)row * 512);
    float4 v[2];
    float sum = 0.f;
#pragma unroll
    for (int j = 0; j < 2; ++j) {
        int u = lane + 64 * j;
        float4 a = xr[u];
        ushort4 s4 = brr[u];
        a.x += su2f(s4.x); a.y += su2f(s4.y); a.z += su2f(s4.z); a.w += su2f(s4.w);
        v[j] = a;
        sum += a.x + a.y + a.z + a.w;
    }
    for (int o = 32; o; o >>= 1) sum += __shfl_xor(sum, o, 64);
    float mean = sum * (1.f / 512.f);
    float vs = 0.f;
#pragma unroll
    for (int j = 0; j < 2; ++j) {
        float dx = v[j].x - mean, dy = v[j].y - mean, dz = v[j].z - mean, dw = v[j].w - mean;
        vs += dx * dx + dy * dy + dz * dz + dw * dw;
    }
    for (int o = 32; o; o >>= 1) vs += __shfl_xor(vs, o, 64);
    float rstd = rsqrtf(vs * (1.f / 512.f) + 1e-5f);
#pragma unroll
    for (int j = 0; j < 2; ++j) {
        int u = lane + 64 * j;
        float4 g4 = ((const float4*)g)[u];
        float4 b4 = ((const float4*)b_)[u];
        float4 o4;
        o4.x = (v[j].x - mean) * rstd * g4.x + b4.x;
        o4.y = (v[j].y - mean) * rstd * g4.y + b4.y;
        o4.z = (v[j].z - mean) * rstd * g4.z + b4.z;
        o4.w = (v[j].w - mean) * rstd * g4.w + b4.w;
        ((float4*)(xout + (size_t)row * 512))[u] = o4;
        ushort4 s4 = { f2bu(o4.x), f2bu(o4.y), f2bu(o4.z), f2bu(o4.w) };
        ((ushort4*)(xbout + (size_t)row * 512))[u] = s4;
    }
}

// env row build + LN -> bf16 env_b. rows = 9216.
__global__ __launch_bounds__(256) void env_ln_kernel(
    const float* __restrict__ astate, const int* __restrict__ atok,
    const float* __restrict__ emb, const int* __restrict__ goal,
    const float* __restrict__ g, const float* __restrict__ b_, bf16* __restrict__ envb)
{
    int row = blockIdx.x * 4 + (threadIdx.x >> 6);
    if (row >= 9216) return;
    int lane = threadIdx.x & 63;
    int s9 = row % 9;
    int bt = row / 9;
    float4 v[2];
    if (s9 < 8) {
        int ar = bt * 8 + s9;
        float msk = (atok[ar] != -1) ? 1.f : 0.f;
#pragma unroll
        for (int j = 0; j < 2; ++j) {
            float4 a = ((const float4*)(astate + (size_t)ar * 512))[lane + 64 * j];
            a.x *= msk; a.y *= msk; a.z *= msk; a.w *= msk;
            v[j] = a;
        }
    } else {
        int gi = goal[bt >> 5];
#pragma unroll
        for (int j = 0; j < 2; ++j)
            v[j] = ((const float4*)(emb + (size_t)gi * 512))[lane + 64 * j];
    }
    float sum = 0.f;
#pragma unroll
    for (int j = 0; j < 2; ++j) sum += v[j].x + v[j].y + v[j].z + v[j].w;
    for (int o = 32; o; o >>= 1) sum += __shfl_xor(sum, o, 64);
    float mean = sum * (1.f / 512.f);
    float vs = 0.f;
#pragma unroll
    for (int j = 0; j < 2; ++j) {
        float dx = v[j].x - mean, dy = v[j].y - mean, dz = v[j].z - mean, dw = v[j].w - mean;
        vs += dx * dx + dy * dy + dz * dz + dw * dw;
    }
    for (int o = 32; o; o >>= 1) vs += __shfl_xor(vs, o, 64);
    float rstd = rsqrtf(vs * (1.f / 512.f) + 1e-5f);
#pragma unroll
    for (int j = 0; j < 2; ++j) {
        int u = lane + 64 * j;
        float4 g4 = ((const float4*)g)[u];
        float4 b4 = ((const float4*)b_)[u];
        ushort4 s4;
        s4.x = f2bu((v[j].x - mean) * rstd * g4.x + b4.x);
        s4.y = f2bu((v[j].y - mean) * rstd * g4.y + b4.y);
        s4.z = f2bu((v[j].z - mean) * rstd * g4.z + b4.z);
        s4.w = f2bu((v[j].w - mean) * rstd * g4.w + b4.w);
        ((ushort4*)(envb + (size_t)row * 512))[u] = s4;
    }
}

__global__ void xcatb_kernel(const int* __restrict__ ids, const float* __restrict__ ego,
                             const bf16* __restrict__ emb_b, bf16* __restrict__ xcat)
{
    int row = blockIdx.x;   // 1024
    int tid = threadIdx.x;  // 128
    int b = row >> 5;
    int id = ids[row];
    bf16x8* dst = (bf16x8*)(xcat + (size_t)row * 576);
    if (tid < 64) {
        dst[tid] = ((const bf16x8*)(emb_b + (size_t)id * 512))[tid];
    } else if (tid == 64) {
        bf16x8 u = {};
        u[0] = f2bs(ego[b * 3 + 0]);
        u[1] = f2bs(ego[b * 3 + 1]);
        u[2] = f2bs(ego[b * 3 + 2]);
        dst[64] = u;
    } else if (tid < 72) {
        bf16x8 z = {};
        dst[tid] = z;
    }
}

__global__ void acatb_kernel(const int* __restrict__ atok, const float* __restrict__ afeat,
                             const bf16* __restrict__ emb_b, bf16* __restrict__ acat)
{
    int row = blockIdx.x;   // 8192
    int tid = threadIdx.x;  // 128
    int tok = atok[row];
    int id = (tok != -1) ? tok : 0;
    bf16x8* dst = (bf16x8*)(acat + (size_t)row * 576);
    if (tid < 64) {
        dst[tid] = ((const bf16x8*)(emb_b + (size_t)id * 512))[tid];
    } else if (tid == 64) {
        bf16x8 u = {};
#pragma unroll
        for (int e = 0; e < 5; ++e) u[e] = f2bs(afeat[(size_t)row * 5 + e]);
        dst[64] = u;
    } else if (tid < 72) {
        bf16x8 z = {};
        dst[tid] = z;
    }
}

__global__ void sel_kernel(const float* __restrict__ x, float* __restrict__ sel, int m0, int cm)
{
    int row = blockIdx.x;   // cm*32
    int ml = row >> 5, b = row & 31;
    int m = m0 + ml;
    const float4* src = (const float4*)(x + ((size_t)(ml * 32 + b) * 32 + (m + 1)) * 512);
    float4* dst = (float4*)(sel + ((size_t)m * 32 + b) * 512);
    dst[threadIdx.x] = src[threadIdx.x];
}

__global__ void fill_kernel(float* __restrict__ o, int n, float v)
{
    int i = blockIdx.x * 256 + threadIdx.x;
    if (i < n) o[i] = v;
}

__global__ void cvtw_kernel(const float* __restrict__ s, unsigned short* __restrict__ d, int n)
{
    int n4 = n >> 2;
    int stride = gridDim.x * blockDim.x;
    for (int i = blockIdx.x * blockDim.x + threadIdx.x; i < n4; i += stride) {
        float4 v = ((const float4*)s)[i];
        ushort4 u = { f2bu(v.x), f2bu(v.y), f2bu(v.z), f2bu(v.w) };
        ((ushort4*)d)[i] = u;
    }
}

__global__ void cvtpad_kernel(const float* __restrict__ s, bf16* __restrict__ d, int Ks)
{
    int row = blockIdx.x;
    int tid = threadIdx.x;
    for (int c = tid; c < 576; c += 256) {
        float v = (c < Ks) ? s[(size_t)row * Ks + c] : 0.f;
        d[(size_t)row * 576 + c] = f2b(v);
    }
}

// ---------------------------------------------------------------------------
extern "C" void kernel_launch(void* const* d_in, const int* in_sizes, int n_in,
                              void* d_out, int out_size, void* d_ws, size_t ws_size,
                              hipStream_t stream)
{
    float* out = (float*)d_out;
    if (n_in < 40) {
        fill_kernel<<<(out_size + 255) / 256, 256, 0, stream>>>(out, out_size, 1e6f);
        return;
    }
    const int*   input_ids = (const int*)d_in[0];
    const float* ego       = (const float*)d_in[1];
    const int*   atok      = (const int*)d_in[2];
    const float* afeat     = (const float*)d_in[3];
    const int*   goal      = (const int*)d_in[4];
    const float* emb       = (const float*)d_in[5];
    const float* se_w1 = (const float*)d_in[6];
    const float* se_b1 = (const float*)d_in[7];
    const float* se_w2 = (const float*)d_in[8];
    const float* se_b2 = (const float*)d_in[9];
    const float* be_w1 = (const float*)d_in[10];
    const float* be_b1 = (const float*)d_in[11];
    const float* be_w2 = (const float*)d_in[12];
    const float* be_b2 = (const float*)d_in[13];
    const float* in_g  = (const float*)d_in[14];
    const float* in_b  = (const float*)d_in[15];
    const float* mem_g = (const float*)d_in[16];
    const float* mem_b = (const float*)d_in[17];
    const float* outn_g = (const float*)d_in[18];
    const float* outn_b = (const float*)d_in[19];
    const float* sa_in_w  = (const float*)d_in[20];
    const float* sa_in_b  = (const float*)d_in[21];
    const float* sa_out_w = (const float*)d_in[22];
    const float* sa_out_b = (const float*)d_in[23];
    const float* ca_in_w  = (const float*)d_in[24];
    const float* ca_in_b  = (const float*)d_in[25];
    const float* ca_out_w = (const float*)d_in[26];
    const float* ca_out_b = (const float*)d_in[27];
    const float* ff_w1 = (const float*)d_in[28];
    const float* ff_b1 = (const float*)d_in[29];
    const float* ff_w2 = (const float*)d_in[30];
    const float* ff_b2 = (const float*)d_in[31];
    const float* ln1_g = (const float*)d_in[32];
    const float* ln1_b = (const float*)d_in[33];
    const float* ln2_g = (const float*)d_in[34];
    const float* ln2_b = (const float*)d_in[35];
    const float* ln3_g = (const float*)d_in[36];
    const float* ln3_b = (const float*)d_in[37];
    const float* proj_w = (const float*)d_in[38];
    const float* proj_b = (const float*)d_in[39];

    auto ALIGN = [](size_t b) { return (b + 255) & ~(size_t)255; };
    uintptr_t base = (uintptr_t)d_ws;
    uintptr_t cur = (base + 255) & ~(uintptr_t)255;
    auto alloc = [&](size_t bytes) -> char* {
        char* r = (char*)cur; cur += (bytes + 255) & ~(size_t)255; return r;
    };

    // ---------------- persistent allocations ----------------
    float* self_state = (float*)alloc((size_t)1024 * 512 * 4);
    bf16*  ss_b       = (bf16*) alloc((size_t)1024 * 512 * 2);
    float* x0         = (float*)alloc((size_t)1024 * 512 * 4);
    bf16*  xb0        = (bf16*) alloc((size_t)1024 * 512 * 2);
    bf16*  q0b        = (bf16*) alloc((size_t)1024 * 512 * 2);
    bf16*  qkv0       = (bf16*) alloc((size_t)1024 * 1536 * 2);
    bf16*  araw0      = (bf16*) alloc((size_t)1024 * 512 * 2);
    bf16*  brnch0     = (bf16*) alloc((size_t)1024 * 512 * 2);
    bf16*  env_b      = (bf16*) alloc((size_t)9216 * 512 * 2);
    bf16*  env_kv     = (bf16*) alloc((size_t)4 * 9216 * 1024 * 2);
    float* sel        = (float*)alloc((size_t)1024 * 512 * 4);
    bf16*  sel_ln_b   = (bf16*) alloc((size_t)1024 * 512 * 2);
    // bf16 weights
    bf16* w_emb   = (bf16*)alloc((size_t)4096 * 512 * 2);
    bf16* w_se1p  = (bf16*)alloc((size_t)512 * 576 * 2);
    bf16* w_be1p  = (bf16*)alloc((size_t)512 * 576 * 2);
    bf16* w_se2   = (bf16*)alloc((size_t)512 * 512 * 2);
    bf16* w_be2   = (bf16*)alloc((size_t)512 * 512 * 2);
    bf16* w_sain  = (bf16*)alloc((size_t)4 * 1536 * 512 * 2);
    bf16* w_saout = (bf16*)alloc((size_t)4 * 512 * 512 * 2);
    bf16* w_cain  = (bf16*)alloc((size_t)4 * 1536 * 512 * 2);
    bf16* w_caout = (bf16*)alloc((size_t)4 * 512 * 512 * 2);
    bf16* w_ff1   = (bf16*)alloc((size_t)4 * 2048 * 512 * 2);
    bf16* w_ff2   = (bf16*)alloc((size_t)4 * 2048 * 512 * 2);
    bf16* w_proj  = (bf16*)alloc((size_t)4096 * 512 * 2);
    uintptr_t big = cur;

    size_t setup_need =
        ALIGN((size_t)1024 * 576 * 2) + ALIGN((size_t)1024 * 512 * 2) +
        ALIGN((size_t)1024 * 512 * 4) +
        ALIGN((size_t)8192 * 576 * 2) + ALIGN((size_t)8192 * 512 * 2) +
        ALIGN((size_t)8192 * 512 * 4);
    auto chunk_need = [&](int c) -> size_t {
        return ALIGN((size_t)c * 1024 * 512 * 4)      // x f32
             + ALIGN((size_t)c * 1024 * 512 * 2)      // xb
             + ALIGN((size_t)c * 1024 * 1536 * 2)     // qkv / q
             + ALIGN((size_t)c * 1024 * 512 * 2)      // araw
             + ALIGN((size_t)c * 1024 * 512 * 2)      // brnch
             + ALIGN((size_t)c * 1024 * 2048 * 2);    // ff1
    };
    int CH = 0;
    if (ws_size > (size_t)(big - base) + 4096) {
        size_t avail = ws_size - (size_t)(big - base) - 4096;
        for (int c = 31; c >= 1; --c)
            if (setup_need <= avail && chunk_need(c) <= avail) { CH = c; break; }
    }
    if (!CH) {
        fill_kernel<<<(out_size + 255) / 256, 256, 0, stream>>>(out, out_size, 1e6f);
        return;
    }

    // ---------------- weight conversion ----------------
    auto cvt = [&](const float* s, bf16* d, size_t n) {
        int n4 = (int)(n >> 2);
        int blocks = (n4 + 255) / 256; if (blocks > 2048) blocks = 2048;
        cvtw_kernel<<<blocks, 256, 0, stream>>>(s, (unsigned short*)d, (int)n);
    };
    cvt(emb, w_emb, (size_t)4096 * 512);
    cvtpad_kernel<<<512, 256, 0, stream>>>(se_w1, w_se1p, 515);
    cvtpad_kernel<<<512, 256, 0, stream>>>(be_w1, w_be1p, 517);
    cvt(se_w2, w_se2, (size_t)512 * 512);
    cvt(be_w2, w_be2, (size_t)512 * 512);
    cvt(sa_in_w, w_sain, (size_t)4 * 1536 * 512);
    cvt(sa_out_w, w_saout, (size_t)4 * 512 * 512);
    cvt(ca_in_w, w_cain, (size_t)4 * 1536 * 512);
    cvt(ca_out_w, w_caout, (size_t)4 * 512 * 512);
    cvt(ff_w1, w_ff1, (size_t)4 * 2048 * 512);
    cvt(ff_w2, w_ff2, (size_t)4 * 2048 * 512);
    cvt(proj_w, w_proj, (size_t)4096 * 512);

    auto launch_mfma = [&](const bf16* A, const bf16* W, const float* bias,
                           void* C, int c_bf16, int M, int N, int K, int relu, int smode) {
        dim3 g(N / 128, (M + 127) / 128);
        mfma_gemm<<<g, 256, 0, stream>>>(A, W, bias, C, M, N, K, c_bf16, relu, smode);
    };

    // ---------------- setup: encoders, env, env_kv ----------------
    {
        uintptr_t sp = big;
        auto salloc = [&](size_t b) -> char* { char* r = (char*)sp; sp += ALIGN(b); return r; };
        bf16*  xcat_b = (bf16*) salloc((size_t)1024 * 576 * 2);
        bf16*  h1b    = (bf16*) salloc((size_t)1024 * 512 * 2);
        float* fused  = (float*)salloc((size_t)1024 * 512 * 4);
        bf16*  acat_b = (bf16*) salloc((size_t)8192 * 576 * 2);
        bf16*  ah1b   = (bf16*) salloc((size_t)8192 * 512 * 2);
        float* astate = (float*)salloc((size_t)8192 * 512 * 4);

        xcatb_kernel<<<1024, 128, 0, stream>>>(input_ids, ego, w_emb, xcat_b);
        launch_mfma(xcat_b, w_se1p, se_b1, h1b, 1, 1024, 512, 576, 1, 0);
        launch_mfma(h1b, w_se2, se_b2, fused, 0, 1024, 512, 512, 0, 0);
        ln_kernel<<<256, 256, 0, stream>>>(fused, in_g, in_b, self_state, ss_b, 1024);

        acatb_kernel<<<8192, 128, 0, stream>>>(atok, afeat, w_emb, acat_b);
        launch_mfma(acat_b, w_be1p, be_b1, ah1b, 1, 8192, 512, 576, 1, 0);
        launch_mfma(ah1b, w_be2, be_b2, astate, 0, 8192, 512, 512, 0, 0);
        env_ln_kernel<<<2304, 256, 0, stream>>>(astate, atok, emb, goal, mem_g, mem_b, env_b);
    }
    // env_kv[l] = env_b @ Wkv_l (9216 x 1024), hoisted out of the chunk loop
    for (int l = 0; l < 4; ++l)
        launch_mfma(env_b, w_cain + (size_t)l * 1536 * 512 + (size_t)512 * 512,
                    ca_in_b + l * 1536 + 512,
                    env_kv + (size_t)l * 9216 * 1024, 1, 9216, 1024, 512, 0, 0);

    // ---------------- layer-0 shared prefix ----------------
    launch_mfma(ss_b, w_sain, sa_in_b, qkv0, 1, 1024, 1536, 512, 0, 0);
    self_attn_mfma<<<32 * 4, 256, 0, stream>>>(qkv0, input_ids, araw0);
    launch_mfma(araw0, w_saout, sa_out_b, brnch0, 1, 1024, 512, 512, 0, 0);
    ln_res2_kernel<<<256, 256, 0, stream>>>(self_state, 0x7fffffff, brnch0,
                                            ln1_g, ln1_b, x0, xb0, 1024);
    launch_mfma(xb0, w_cain, ca_in_b, q0b, 1, 1024, 512, 512, 0, 0);

    // ---------------- decode ----------------
    {
        uintptr_t sp = big;
        auto salloc = [&](size_t b) -> char* { char* r = (char*)sp; sp += ALIGN(b); return r; };
        float* x     = (float*)salloc((size_t)CH * 1024 * 512 * 4);
        bf16*  xb    = (bf16*) salloc((size_t)CH * 1024 * 512 * 2);
        bf16*  qkv   = (bf16*) salloc((size_t)CH * 1024 * 1536 * 2);
        bf16*  araw  = (bf16*) salloc((size_t)CH * 1024 * 512 * 2);
        bf16*  brnch = (bf16*) salloc((size_t)CH * 1024 * 512 * 2);
        bf16*  ff1b  = (bf16*) salloc((size_t)CH * 1024 * 2048 * 2);

        for (int m0 = 0; m0 < 31; m0 += CH) {
            int cm = (31 - m0) < CH ? (31 - m0) : CH;
            int Mr = cm * 1024;
            // --- layer 0 (shared self-attn prefix + shared q precomputed) ---
            cross_attn_mfma<<<cm * 32 * 4, 256, 0, stream>>>(q0b, 1, env_kv, araw, m0);
            launch_mfma(araw, w_caout, ca_out_b, brnch, 1, Mr, 512, 512, 0, 0);
            ln_res2_kernel<<<(Mr + 3) / 4, 256, 0, stream>>>(x0, 1023, brnch,
                                                             ln2_g, ln2_b, x, xb, Mr);
            launch_mfma(xb, w_ff1, ff_b1, ff1b, 1, Mr, 2048, 512, 1, 0);
            launch_mfma(ff1b, w_ff2, ff_b2, brnch, 1, Mr, 512, 2048, 0, 0);
            ln_res2_kernel<<<(Mr + 3) / 4, 256, 0, stream>>>(x, 0x7fffffff, brnch,
                                                             ln3_g, ln3_b, x, xb, Mr);
            // --- layers 1..3 ---
            for (int l = 1; l < 4; ++l) {
                launch_mfma(xb, w_sain + (size_t)l * 1536 * 512, sa_in_b + l * 1536,
                            qkv, 1, Mr, 1536, 512, 0, 0);
                self_attn_mfma<<<cm * 32 * 4, 256, 0, stream>>>(qkv, input_ids, araw);
                launch_mfma(araw, w_saout + (size_t)l * 512 * 512, sa_out_b + l * 512,
                            brnch, 1, Mr, 512, 512, 0, 0);
                ln_res2_kernel<<<(Mr + 3) / 4, 256, 0, stream>>>(x, 0x7fffffff, brnch,
                                                                 ln1_g + l * 512, ln1_b + l * 512, x, xb, Mr);
                launch_mfma(xb, w_cain + (size_t)l * 1536 * 512, ca_in_b + l * 1536,
                            qkv, 1, Mr, 512, 512, 0, 0);
                cross_attn_mfma<<<cm * 32 * 4, 256, 0, stream>>>(
                    qkv, 0, env_kv + (size_t)l * 9216 * 1024, araw, m0);
                launch_mfma(araw, w_caout + (size_t)l * 512 * 512, ca_out_b + l * 512,
                            brnch, 1, Mr, 512, 512, 0, 0);
                ln_res2_kernel<<<(Mr + 3) / 4, 256, 0, stream>>>(x, 0x7fffffff, brnch,
                                                                 ln2_g + l * 512, ln2_b + l * 512, x, xb, Mr);
                launch_mfma(xb, w_ff1 + (size_t)l * 2048 * 512, ff_b1 + l * 2048,
                            ff1b, 1, Mr, 2048, 512, 1, 0);
                launch_mfma(ff1b, w_ff2 + (size_t)l * 512 * 2048, ff_b2 + l * 512,
                            brnch, 1, Mr, 512, 2048, 0, 0);
                ln_res2_kernel<<<(Mr + 3) / 4, 256, 0, stream>>>(x, 0x7fffffff, brnch,
                                                                 ln3_g + l * 512, ln3_b + l * 512, x, xb, Mr);
            }
            sel_kernel<<<cm * 32, 128, 0, stream>>>(x, sel, m0, cm);
        }
    }

    // ---------------- final: LN + vocab projection (transposed store) ----------------
    ln_kernel<<<248, 256, 0, stream>>>(sel, outn_g, outn_b, (float*)nullptr, sel_ln_b, 992);
    launch_mfma(sel_ln_b, w_proj, proj_b, out, 0, 992, 4096, 512, 0, 1);
}

// Round 10
// 3051.265 us; speedup vs baseline: 1.8218x; 1.2530x over previous
//
#include <hip/hip_runtime.h>
#include <hip/hip_bf16.h>
#include <stdint.h>

typedef __hip_bfloat16 bf16;
typedef __attribute__((ext_vector_type(8))) short bf16x8;
typedef __attribute__((ext_vector_type(4))) float f32x4;

__device__ __forceinline__ float b2f(bf16 v) { return __bfloat162float(v); }
__device__ __forceinline__ bf16 f2b(float v) { return __float2bfloat16(v); }
__device__ __forceinline__ unsigned short f2bu(float v) {
    bf16 h = __float2bfloat16(v);
    return *(unsigned short*)&h;
}
__device__ __forceinline__ short f2bs(float v) {
    bf16 h = __float2bfloat16(v);
    return *(short*)&h;
}
__device__ __forceinline__ float su2f(unsigned short u) {
    unsigned int x = ((unsigned int)u) << 16;
    return *(float*)&x;
}

__device__ __forceinline__ void gload_lds16(const void* g, void* l) {
    __builtin_amdgcn_global_load_lds((const __attribute__((address_space(1))) void*)g,
                                     (__attribute__((address_space(3))) void*)l, 16, 0, 0);
}

// swizzled byte offset in [row][32 kk] bf16 tile, 80B row stride (attn tiles)
__device__ __forceinline__ int swz_byte(int row, int kk) {
    return row * 80 + 2 * (kk & 7) + 16 * ((kk >> 3) ^ (row & 3));
}

// ---------------------------------------------------------------------------
// MFMA bf16 GEMM: C[M,N] = act(A[M,K]@W[N,K]^T + bias). 128x128 tile, BK=64.
// Throughput scales with blocks/CU (cross-block wave overlap hides barrier
// drains) -> larger chunk CH directly speeds the N=512 projections.
// ---------------------------------------------------------------------------
__global__ __launch_bounds__(256) void mfma_gemm(
    const bf16* __restrict__ A, const bf16* __restrict__ W,
    const float* __restrict__ bias, void* __restrict__ C,
    int M, int N, int K, int c_bf16, int relu, int store_mode)
{
    __shared__ bf16 As[128 * 64];
    __shared__ bf16 Bs[128 * 64];
    const int gx = gridDim.x;
    const int nwg = gx * gridDim.y;
    const int orig = blockIdx.y * gx + blockIdx.x;
    const int qq = nwg >> 3, rr8 = nwg & 7;
    const int xcd = orig & 7, lid = orig >> 3;
    const int wgid = (xcd < rr8 ? xcd * (qq + 1) : rr8 * (qq + 1) + (xcd - rr8) * qq) + lid;
    const int m0 = (wgid / gx) * 128, n0 = (wgid % gx) * 128;

    const int tid = threadIdx.x;
    const int wave = tid >> 6, lane = tid & 63;
    const int wr = wave >> 1, wc = wave & 1;
    const int fr = lane & 15, fg = lane >> 4;
    f32x4 acc[4][4] = {};

    const int srow = lane >> 3;
    const int sunit = (lane & 7) ^ srow;

    for (int k0 = 0; k0 < K; k0 += 64) {
#pragma unroll
        for (int c = 0; c < 4; ++c) {
            const int chunk = wave * 4 + c;
            const int arow = m0 + chunk * 8 + srow;
            const int brow = n0 + chunk * 8 + srow;
            gload_lds16(A + (size_t)arow * K + k0 + sunit * 8, (char*)As + chunk * 1024);
            gload_lds16(W + (size_t)brow * K + k0 + sunit * 8, (char*)Bs + chunk * 1024);
        }
        __syncthreads();
#pragma unroll
        for (int kk = 0; kk < 64; kk += 32) {
            bf16x8 af[4], bw[4];
            const int bo = (kk + fg * 8) * 2;
#pragma unroll
            for (int t = 0; t < 4; ++t) {
                const int ra = wr * 64 + t * 16 + fr;
                af[t] = *(const bf16x8*)((const char*)As + ra * 128 + (bo ^ ((ra & 7) << 4)));
                const int rb = wc * 64 + t * 16 + fr;
                bw[t] = *(const bf16x8*)((const char*)Bs + rb * 128 + (bo ^ ((rb & 7) << 4)));
            }
#pragma unroll
            for (int mt = 0; mt < 4; ++mt)
#pragma unroll
                for (int nt = 0; nt < 4; ++nt)
                    acc[mt][nt] = __builtin_amdgcn_mfma_f32_16x16x32_bf16(
                        af[mt], bw[nt], acc[mt][nt], 0, 0, 0);
        }
        __syncthreads();
    }
#pragma unroll
    for (int mt = 0; mt < 4; ++mt) {
#pragma unroll
        for (int r = 0; r < 4; ++r) {
            const int m = m0 + wr * 64 + mt * 16 + fg * 4 + r;
            if (m >= M) continue;
            size_t orow = (size_t)m;
            if (store_mode == 1) orow = (size_t)(m & 31) * 31 + (m >> 5);
#pragma unroll
            for (int nt = 0; nt < 4; ++nt) {
                const int n = n0 + wc * 64 + nt * 16 + fr;
                float v = acc[mt][nt][r] + bias[n];
                if (relu) v = fmaxf(v, 0.f);
                if (c_bf16) ((bf16*)C)[orow * N + n] = f2b(v);
                else        ((float*)C)[orow * N + n] = v;
            }
        }
    }
}

// ---------------------------------------------------------------------------
// MFMA self-attention. Block = (mb, head-pair). T=32, dh=64. qkv row stride 1536.
// ---------------------------------------------------------------------------
__global__ __launch_bounds__(256) void self_attn_mfma(
    const bf16* __restrict__ qkv, const int* __restrict__ input_ids,
    bf16* __restrict__ attn_out)
{
    const int bid = blockIdx.x;
    const int hp = bid & 3;
    const int mb = bid >> 2;
    const int b = mb & 31;
    const size_t rowbase = (size_t)mb * 32;

    __shared__ __align__(16) char vt_raw[2][64 * 80];
    __shared__ __align__(16) char ps_raw[4][16 * 80];
    __shared__ float kpmv[32];

    const int tid = threadIdx.x;
    {
        const int r = tid & 31, u = tid >> 5;
#pragma unroll
        for (int e2 = 0; e2 < 2; ++e2) {
            const int h = hp * 2 + e2;
            bf16x8 v8 = *(const bf16x8*)(qkv + (rowbase + r) * 1536 + 1024 + h * 64 + u * 8);
#pragma unroll
            for (int j = 0; j < 8; ++j)
                *(short*)(vt_raw[e2] + swz_byte(u * 8 + j, r)) = v8[j];
        }
    }
    if (tid < 32) kpmv[tid] = (input_ids[b * 32 + tid] == 0) ? -1e9f : 0.f;
    __syncthreads();

    const int wave = tid >> 6, lane = tid & 63;
    const int e = wave >> 1;
    const int h = hp * 2 + e;
    const int qi = wave & 1;
    const int c = lane & 15, fg = lane >> 4;

    const bf16* qrow = qkv + (rowbase + qi * 16 + c) * 1536 + h * 64;
    bf16x8 af0 = *(const bf16x8*)(qrow + fg * 8);
    bf16x8 af1 = *(const bf16x8*)(qrow + 32 + fg * 8);
    f32x4 s[2];
#pragma unroll
    for (int kj = 0; kj < 2; ++kj) {
        const bf16* krow = qkv + (rowbase + kj * 16 + c) * 1536 + 512 + h * 64;
        bf16x8 b0 = *(const bf16x8*)(krow + fg * 8);
        bf16x8 b1 = *(const bf16x8*)(krow + 32 + fg * 8);
        f32x4 a = {};
        a = __builtin_amdgcn_mfma_f32_16x16x32_bf16(af0, b0, a, 0, 0, 0);
        a = __builtin_amdgcn_mfma_f32_16x16x32_bf16(af1, b1, a, 0, 0, 0);
        s[kj] = a;
    }
#pragma unroll
    for (int r = 0; r < 4; ++r) {
        const int qg = qi * 16 + fg * 4 + r;
        float v0 = s[0][r] * 0.125f + kpmv[c];
        float v1 = s[1][r] * 0.125f + kpmv[16 + c];
        if (c > qg) v0 = -1e9f;
        if (16 + c > qg) v1 = -1e9f;
        float m = fmaxf(v0, v1);
        m = fmaxf(m, __shfl_xor(m, 1)); m = fmaxf(m, __shfl_xor(m, 2));
        m = fmaxf(m, __shfl_xor(m, 4)); m = fmaxf(m, __shfl_xor(m, 8));
        float e0 = __expf(v0 - m), e1 = __expf(v1 - m);
        float sm = e0 + e1;
        sm += __shfl_xor(sm, 1); sm += __shfl_xor(sm, 2);
        sm += __shfl_xor(sm, 4); sm += __shfl_xor(sm, 8);
        float inv = 1.f / sm;
        *(short*)(ps_raw[wave] + swz_byte(fg * 4 + r, c))      = f2bs(e0 * inv);
        *(short*)(ps_raw[wave] + swz_byte(fg * 4 + r, 16 + c)) = f2bs(e1 * inv);
    }
    bf16x8 pa = *(const bf16x8*)(ps_raw[wave] + c * 80 + 16 * (fg ^ (c & 3)));
    f32x4 o[4];
#pragma unroll
    for (int dj = 0; dj < 4; ++dj) {
        bf16x8 bv = *(const bf16x8*)(vt_raw[e] + (dj * 16 + c) * 80 + 16 * (fg ^ (c & 3)));
        f32x4 a = {};
        o[dj] = __builtin_amdgcn_mfma_f32_16x16x32_bf16(pa, bv, a, 0, 0, 0);
    }
#pragma unroll
    for (int dj = 0; dj < 4; ++dj)
#pragma unroll
        for (int r = 0; r < 4; ++r)
            attn_out[(rowbase + qi * 16 + fg * 4 + r) * 512 + h * 64 + dj * 16 + c] = f2b(o[dj][r]);
}

// ---------------------------------------------------------------------------
// MFMA cross-attention reading env_kv (9216 x 1024 = k|v) via computed gather.
// ---------------------------------------------------------------------------
__device__ __forceinline__ int env_idx(int m, int b, int j) {
    int gi = j / 9, sp = j - gi * 9;
    int t = m - 1 + gi;
    t = t < 0 ? 0 : (t > 31 ? 31 : t);
    return (b * 32 + t) * 9 + sp;
}

__global__ __launch_bounds__(256) void cross_attn_mfma(
    const bf16* __restrict__ q, int qshared, const bf16* __restrict__ ekv,
    bf16* __restrict__ attn_out, int m0glob)
{
    const int bid = blockIdx.x;
    const int hp = bid & 3;
    const int mb = bid >> 2;
    const int b = mb & 31;
    const int m = m0glob + (mb >> 5);
    const size_t qb = (size_t)(qshared ? b : mb) * 32;
    const size_t ob = (size_t)mb * 32;

    __shared__ __align__(16) char vt_raw[2][64 * 80];
    __shared__ __align__(16) char ps_raw[4][16 * 80];

    const int tid = threadIdx.x;
    {
        const int r = tid & 31, u = tid >> 5;
        const size_t erow = (size_t)env_idx(m, b, r) * 1024;
#pragma unroll
        for (int e2 = 0; e2 < 2; ++e2) {
            const int h = hp * 2 + e2;
            bf16x8 v8 = *(const bf16x8*)(ekv + erow + 512 + h * 64 + u * 8);
#pragma unroll
            for (int j = 0; j < 8; ++j)
                *(short*)(vt_raw[e2] + swz_byte(u * 8 + j, r)) = v8[j];
        }
    }
    __syncthreads();

    const int wave = tid >> 6, lane = tid & 63;
    const int e = wave >> 1;
    const int h = hp * 2 + e;
    const int qi = wave & 1;
    const int c = lane & 15, fg = lane >> 4;

    const bf16* qrow = q + (qb + qi * 16 + c) * 512 + h * 64;
    bf16x8 af0 = *(const bf16x8*)(qrow + fg * 8);
    bf16x8 af1 = *(const bf16x8*)(qrow + 32 + fg * 8);
    f32x4 s[2];
#pragma unroll
    for (int kj = 0; kj < 2; ++kj) {
        const size_t erow = (size_t)env_idx(m, b, kj * 16 + c) * 1024;
        bf16x8 b0 = *(const bf16x8*)(ekv + erow + h * 64 + fg * 8);
        bf16x8 b1 = *(const bf16x8*)(ekv + erow + h * 64 + 32 + fg * 8);
        f32x4 a = {};
        a = __builtin_amdgcn_mfma_f32_16x16x32_bf16(af0, b0, a, 0, 0, 0);
        a = __builtin_amdgcn_mfma_f32_16x16x32_bf16(af1, b1, a, 0, 0, 0);
        s[kj] = a;
    }
#pragma unroll
    for (int r = 0; r < 4; ++r) {
        float v0 = s[0][r] * 0.125f;
        float v1 = (16 + c < 27) ? s[1][r] * 0.125f : -1e9f;
        float m2 = fmaxf(v0, v1);
        m2 = fmaxf(m2, __shfl_xor(m2, 1)); m2 = fmaxf(m2, __shfl_xor(m2, 2));
        m2 = fmaxf(m2, __shfl_xor(m2, 4)); m2 = fmaxf(m2, __shfl_xor(m2, 8));
        float e0 = __expf(v0 - m2), e1 = __expf(v1 - m2);
        float sm = e0 + e1;
        sm += __shfl_xor(sm, 1); sm += __shfl_xor(sm, 2);
        sm += __shfl_xor(sm, 4); sm += __shfl_xor(sm, 8);
        float inv = 1.f / sm;
        *(short*)(ps_raw[wave] + swz_byte(fg * 4 + r, c))      = f2bs(e0 * inv);
        *(short*)(ps_raw[wave] + swz_byte(fg * 4 + r, 16 + c)) = f2bs(e1 * inv);
    }
    bf16x8 pa = *(const bf16x8*)(ps_raw[wave] + c * 80 + 16 * (fg ^ (c & 3)));
    f32x4 o[4];
#pragma unroll
    for (int dj = 0; dj < 4; ++dj) {
        bf16x8 bv = *(const bf16x8*)(vt_raw[e] + (dj * 16 + c) * 80 + 16 * (fg ^ (c & 3)));
        f32x4 a = {};
        o[dj] = __builtin_amdgcn_mfma_f32_16x16x32_bf16(pa, bv, a, 0, 0, 0);
    }
#pragma unroll
    for (int dj = 0; dj < 4; ++dj)
#pragma unroll
        for (int r = 0; r < 4; ++r)
            attn_out[(ob + qi * 16 + fg * 4 + r) * 512 + h * 64 + dj * 16 + c] = f2b(o[dj][r]);
}

// ---------------------------------------------------------------------------
// LayerNorm over D=512; f32 in, bf16 out (encoder fused-LN only).
// ---------------------------------------------------------------------------
__global__ __launch_bounds__(256) void ln_kernel(
    const float* __restrict__ x, const float* __restrict__ g,
    const float* __restrict__ b_, bf16* __restrict__ outb, int rows)
{
    int row = blockIdx.x * 4 + (threadIdx.x >> 6);
    if (row >= rows) return;
    int lane = threadIdx.x & 63;
    const float4* xr = (const float4*)(x + (size_t)row * 512);
    float4 v[2];
    float sum = 0.f;
#pragma unroll
    for (int j = 0; j < 2; ++j) {
        v[j] = xr[lane + 64 * j];
        sum += v[j].x + v[j].y + v[j].z + v[j].w;
    }
    for (int o = 32; o; o >>= 1) sum += __shfl_xor(sum, o, 64);
    float mean = sum * (1.f / 512.f);
    float vs = 0.f;
#pragma unroll
    for (int j = 0; j < 2; ++j) {
        float dx = v[j].x - mean, dy = v[j].y - mean, dz = v[j].z - mean, dw = v[j].w - mean;
        vs += dx * dx + dy * dy + dz * dz + dw * dw;
    }
    for (int o = 32; o; o >>= 1) vs += __shfl_xor(vs, o, 64);
    float rstd = rsqrtf(vs * (1.f / 512.f) + 1e-5f);
#pragma unroll
    for (int j = 0; j < 2; ++j) {
        int u = lane + 64 * j;
        float4 g4 = ((const float4*)g)[u];
        float4 b4 = ((const float4*)b_)[u];
        ushort4 s4;
        s4.x = f2bu((v[j].x - mean) * rstd * g4.x + b4.x);
        s4.y = f2bu((v[j].y - mean) * rstd * g4.y + b4.y);
        s4.z = f2bu((v[j].z - mean) * rstd * g4.z + b4.z);
        s4.w = f2bu((v[j].w - mean) * rstd * g4.w + b4.w);
        ((ushort4*)(outb + (size_t)row * 512))[u] = s4;
    }
}

// xbout = LN(xin[row&mask] + br[row])  -- all bf16 storage, f32 math.
// br may be null (plain LN of xin).
__global__ __launch_bounds__(256) void ln_res2_kernel(
    const bf16* __restrict__ xin, int rowmask, const bf16* __restrict__ br,
    const float* __restrict__ g, const float* __restrict__ b_,
    bf16* __restrict__ xbout, int rows)
{
    int row = blockIdx.x * 4 + (threadIdx.x >> 6);
    if (row >= rows) return;
    int lane = threadIdx.x & 63;
    const ushort4* xr = (const ushort4*)(xin + (size_t)(row & rowmask) * 512);
    const ushort4* brr = br ? (const ushort4*)(br + (size_t)row * 512) : nullptr;
    float4 v[2];
    float sum = 0.f;
#pragma unroll
    for (int j = 0; j < 2; ++j) {
        int u = lane + 64 * j;
        ushort4 a4 = xr[u];
        float4 a = { su2f(a4.x), su2f(a4.y), su2f(a4.z), su2f(a4.w) };
        if (brr) {
            ushort4 s4 = brr[u];
            a.x += su2f(s4.x); a.y += su2f(s4.y); a.z += su2f(s4.z); a.w += su2f(s4.w);
        }
        v[j] = a;
        sum += a.x + a.y + a.z + a.w;
    }
    for (int o = 32; o; o >>= 1) sum += __shfl_xor(sum, o, 64);
    float mean = sum * (1.f / 512.f);
    float vs = 0.f;
#pragma unroll
    for (int j = 0; j < 2; ++j) {
        float dx = v[j].x - mean, dy = v[j].y - mean, dz = v[j].z - mean, dw = v[j].w - mean;
        vs += dx * dx + dy * dy + dz * dz + dw * dw;
    }
    for (int o = 32; o; o >>= 1) vs += __shfl_xor(vs, o, 64);
    float rstd = rsqrtf(vs * (1.f / 512.f) + 1e-5f);
#pragma unroll
    for (int j = 0; j < 2; ++j) {
        int u = lane + 64 * j;
        float4 g4 = ((const float4*)g)[u];
        float4 b4 = ((const float4*)b_)[u];
        ushort4 s4;
        s4.x = f2bu((v[j].x - mean) * rstd * g4.x + b4.x);
        s4.y = f2bu((v[j].y - mean) * rstd * g4.y + b4.y);
        s4.z = f2bu((v[j].z - mean) * rstd * g4.z + b4.z);
        s4.w = f2bu((v[j].w - mean) * rstd * g4.w + b4.w);
        ((ushort4*)(xbout + (size_t)row * 512))[u] = s4;
    }
}

// env row build + LN -> bf16 env_b. rows = 9216.
__global__ __launch_bounds__(256) void env_ln_kernel(
    const float* __restrict__ astate, const int* __restrict__ atok,
    const float* __restrict__ emb, const int* __restrict__ goal,
    const float* __restrict__ g, const float* __restrict__ b_, bf16* __restrict__ envb)
{
    int row = blockIdx.x * 4 + (threadIdx.x >> 6);
    if (row >= 9216) return;
    int lane = threadIdx.x & 63;
    int s9 = row % 9;
    int bt = row / 9;
    float4 v[2];
    if (s9 < 8) {
        int ar = bt * 8 + s9;
        float msk = (atok[ar] != -1) ? 1.f : 0.f;
#pragma unroll
        for (int j = 0; j < 2; ++j) {
            float4 a = ((const float4*)(astate + (size_t)ar * 512))[lane + 64 * j];
            a.x *= msk; a.y *= msk; a.z *= msk; a.w *= msk;
            v[j] = a;
        }
    } else {
        int gi = goal[bt >> 5];
#pragma unroll
        for (int j = 0; j < 2; ++j)
            v[j] = ((const float4*)(emb + (size_t)gi * 512))[lane + 64 * j];
    }
    float sum = 0.f;
#pragma unroll
    for (int j = 0; j < 2; ++j) sum += v[j].x + v[j].y + v[j].z + v[j].w;
    for (int o = 32; o; o >>= 1) sum += __shfl_xor(sum, o, 64);
    float mean = sum * (1.f / 512.f);
    float vs = 0.f;
#pragma unroll
    for (int j = 0; j < 2; ++j) {
        float dx = v[j].x - mean, dy = v[j].y - mean, dz = v[j].z - mean, dw = v[j].w - mean;
        vs += dx * dx + dy * dy + dz * dz + dw * dw;
    }
    for (int o = 32; o; o >>= 1) vs += __shfl_xor(vs, o, 64);
    float rstd = rsqrtf(vs * (1.f / 512.f) + 1e-5f);
#pragma unroll
    for (int j = 0; j < 2; ++j) {
        int u = lane + 64 * j;
        float4 g4 = ((const float4*)g)[u];
        float4 b4 = ((const float4*)b_)[u];
        ushort4 s4;
        s4.x = f2bu((v[j].x - mean) * rstd * g4.x + b4.x);
        s4.y = f2bu((v[j].y - mean) * rstd * g4.y + b4.y);
        s4.z = f2bu((v[j].z - mean) * rstd * g4.z + b4.z);
        s4.w = f2bu((v[j].w - mean) * rstd * g4.w + b4.w);
        ((ushort4*)(envb + (size_t)row * 512))[u] = s4;
    }
}

__global__ void xcatb_kernel(const int* __restrict__ ids, const float* __restrict__ ego,
                             const bf16* __restrict__ emb_b, bf16* __restrict__ xcat)
{
    int row = blockIdx.x;   // 1024
    int tid = threadIdx.x;  // 128
    int b = row >> 5;
    int id = ids[row];
    bf16x8* dst = (bf16x8*)(xcat + (size_t)row * 576);
    if (tid < 64) {
        dst[tid] = ((const bf16x8*)(emb_b + (size_t)id * 512))[tid];
    } else if (tid == 64) {
        bf16x8 u = {};
        u[0] = f2bs(ego[b * 3 + 0]);
        u[1] = f2bs(ego[b * 3 + 1]);
        u[2] = f2bs(ego[b * 3 + 2]);
        dst[64] = u;
    } else if (tid < 72) {
        bf16x8 z = {};
        dst[tid] = z;
    }
}

__global__ void acatb_kernel(const int* __restrict__ atok, const float* __restrict__ afeat,
                             const bf16* __restrict__ emb_b, bf16* __restrict__ acat)
{
    int row = blockIdx.x;   // 8192
    int tid = threadIdx.x;  // 128
    int tok = atok[row];
    int id = (tok != -1) ? tok : 0;
    bf16x8* dst = (bf16x8*)(acat + (size_t)row * 576);
    if (tid < 64) {
        dst[tid] = ((const bf16x8*)(emb_b + (size_t)id * 512))[tid];
    } else if (tid == 64) {
        bf16x8 u = {};
#pragma unroll
        for (int e = 0; e < 5; ++e) u[e] = f2bs(afeat[(size_t)row * 5 + e]);
        dst[64] = u;
    } else if (tid < 72) {
        bf16x8 z = {};
        dst[tid] = z;
    }
}

// sel_b[(m*32+b)] = xb[(ml*32+b)*32 + (m+1)]  (bf16)
__global__ void sel_kernel(const bf16* __restrict__ x, bf16* __restrict__ sel, int m0, int cm)
{
    int row = blockIdx.x;   // cm*32
    int ml = row >> 5, b = row & 31;
    int m = m0 + ml;
    const ushort4* src = (const ushort4*)(x + ((size_t)(ml * 32 + b) * 32 + (m + 1)) * 512);
    ushort4* dst = (ushort4*)(sel + ((size_t)m * 32 + b) * 512);
    dst[threadIdx.x] = src[threadIdx.x];   // 128 thr x 8B = 1KB row
}

__global__ void fill_kernel(float* __restrict__ o, int n, float v)
{
    int i = blockIdx.x * 256 + threadIdx.x;
    if (i < n) o[i] = v;
}

__global__ void cvtw_kernel(const float* __restrict__ s, unsigned short* __restrict__ d, int n)
{
    int n4 = n >> 2;
    int stride = gridDim.x * blockDim.x;
    for (int i = blockIdx.x * blockDim.x + threadIdx.x; i < n4; i += stride) {
        float4 v = ((const float4*)s)[i];
        ushort4 u = { f2bu(v.x), f2bu(v.y), f2bu(v.z), f2bu(v.w) };
        ((ushort4*)d)[i] = u;
    }
}

__global__ void cvtpad_kernel(const float* __restrict__ s, bf16* __restrict__ d, int Ks)
{
    int row = blockIdx.x;
    int tid = threadIdx.x;
    for (int c = tid; c < 576; c += 256) {
        float v = (c < Ks) ? s[(size_t)row * Ks + c] : 0.f;
        d[(size_t)row * 576 + c] = f2b(v);
    }
}

// ---------------------------------------------------------------------------
extern "C" void kernel_launch(void* const* d_in, const int* in_sizes, int n_in,
                              void* d_out, int out_size, void* d_ws, size_t ws_size,
                              hipStream_t stream)
{
    float* out = (float*)d_out;
    if (n_in < 40) {
        fill_kernel<<<(out_size + 255) / 256, 256, 0, stream>>>(out, out_size, 1e6f);
        return;
    }
    const int*   input_ids = (const int*)d_in[0];
    const float* ego       = (const float*)d_in[1];
    const int*   atok      = (const int*)d_in[2];
    const float* afeat     = (const float*)d_in[3];
    const int*   goal      = (const int*)d_in[4];
    const float* emb       = (const float*)d_in[5];
    const float* se_w1 = (const float*)d_in[6];
    const float* se_b1 = (const float*)d_in[7];
    const float* se_w2 = (const float*)d_in[8];
    const float* se_b2 = (const float*)d_in[9];
    const float* be_w1 = (const float*)d_in[10];
    const float* be_b1 = (const float*)d_in[11];
    const float* be_w2 = (const float*)d_in[12];
    const float* be_b2 = (const float*)d_in[13];
    const float* in_g  = (const float*)d_in[14];
    const float* in_b  = (const float*)d_in[15];
    const float* mem_g = (const float*)d_in[16];
    const float* mem_b = (const float*)d_in[17];
    const float* outn_g = (const float*)d_in[18];
    const float* outn_b = (const float*)d_in[19];
    const float* sa_in_w  = (const float*)d_in[20];
    const float* sa_in_b  = (const float*)d_in[21];
    const float* sa_out_w = (const float*)d_in[22];
    const float* sa_out_b = (const float*)d_in[23];
    const float* ca_in_w  = (const float*)d_in[24];
    const float* ca_in_b  = (const float*)d_in[25];
    const float* ca_out_w = (const float*)d_in[26];
    const float* ca_out_b = (const float*)d_in[27];
    const float* ff_w1 = (const float*)d_in[28];
    const float* ff_b1 = (const float*)d_in[29];
    const float* ff_w2 = (const float*)d_in[30];
    const float* ff_b2 = (const float*)d_in[31];
    const float* ln1_g = (const float*)d_in[32];
    const float* ln1_b = (const float*)d_in[33];
    const float* ln2_g = (const float*)d_in[34];
    const float* ln2_b = (const float*)d_in[35];
    const float* ln3_g = (const float*)d_in[36];
    const float* ln3_b = (const float*)d_in[37];
    const float* proj_w = (const float*)d_in[38];
    const float* proj_b = (const float*)d_in[39];

    auto ALIGN = [](size_t b) { return (b + 255) & ~(size_t)255; };
    uintptr_t base = (uintptr_t)d_ws;
    uintptr_t cur = (base + 255) & ~(uintptr_t)255;
    auto alloc = [&](size_t bytes) -> char* {
        char* r = (char*)cur; cur += (bytes + 255) & ~(size_t)255; return r;
    };

    // ---------------- persistent allocations (bf16 residual stream) ----------
    bf16*  ss_b       = (bf16*) alloc((size_t)1024 * 512 * 2);
    bf16*  xb0        = (bf16*) alloc((size_t)1024 * 512 * 2);
    bf16*  q0b        = (bf16*) alloc((size_t)1024 * 512 * 2);
    bf16*  qkv0       = (bf16*) alloc((size_t)1024 * 1536 * 2);
    bf16*  araw0      = (bf16*) alloc((size_t)1024 * 512 * 2);
    bf16*  brnch0     = (bf16*) alloc((size_t)1024 * 512 * 2);
    bf16*  env_b      = (bf16*) alloc((size_t)9216 * 512 * 2);
    bf16*  env_kv1    = (bf16*) alloc((size_t)9216 * 1024 * 2);   // single-layer kv
    bf16*  sel_b      = (bf16*) alloc((size_t)1024 * 512 * 2);
    bf16*  sel_ln_b   = (bf16*) alloc((size_t)1024 * 512 * 2);
    // bf16 weights
    bf16* w_emb   = (bf16*)alloc((size_t)4096 * 512 * 2);
    bf16* w_se1p  = (bf16*)alloc((size_t)512 * 576 * 2);
    bf16* w_be1p  = (bf16*)alloc((size_t)512 * 576 * 2);
    bf16* w_se2   = (bf16*)alloc((size_t)512 * 512 * 2);
    bf16* w_be2   = (bf16*)alloc((size_t)512 * 512 * 2);
    bf16* w_sain  = (bf16*)alloc((size_t)4 * 1536 * 512 * 2);
    bf16* w_saout = (bf16*)alloc((size_t)4 * 512 * 512 * 2);
    bf16* w_cain  = (bf16*)alloc((size_t)4 * 1536 * 512 * 2);
    bf16* w_caout = (bf16*)alloc((size_t)4 * 512 * 512 * 2);
    bf16* w_ff1   = (bf16*)alloc((size_t)4 * 2048 * 512 * 2);
    bf16* w_ff2   = (bf16*)alloc((size_t)4 * 2048 * 512 * 2);
    bf16* w_proj  = (bf16*)alloc((size_t)4096 * 512 * 2);
    uintptr_t big = cur;

    size_t setup_need =
        ALIGN((size_t)1024 * 576 * 2) + ALIGN((size_t)1024 * 512 * 2) +
        ALIGN((size_t)1024 * 512 * 4) +
        ALIGN((size_t)8192 * 576 * 2) + ALIGN((size_t)8192 * 512 * 2) +
        ALIGN((size_t)8192 * 512 * 4);
    // chunk: xb (1.05c) + union qkv/ff1b (4.19c) + araw (1.05c) + brnch (1.05c)
    auto chunk_need = [&](int c) -> size_t {
        return ALIGN((size_t)c * 1024 * 512 * 2)
             + ALIGN((size_t)c * 1024 * 2048 * 2)
             + ALIGN((size_t)c * 1024 * 512 * 2)
             + ALIGN((size_t)c * 1024 * 512 * 2);
    };
    int CH = 0;
    if (ws_size > (size_t)(big - base) + 4096) {
        size_t avail = ws_size - (size_t)(big - base) - 4096;
        for (int c = 31; c >= 1; --c)
            if (setup_need <= avail && chunk_need(c) <= avail) { CH = c; break; }
    }
    if (!CH) {
        fill_kernel<<<(out_size + 255) / 256, 256, 0, stream>>>(out, out_size, 1e6f);
        return;
    }

    // ---------------- weight conversion ----------------
    auto cvt = [&](const float* s, bf16* d, size_t n) {
        int n4 = (int)(n >> 2);
        int blocks = (n4 + 255) / 256; if (blocks > 2048) blocks = 2048;
        cvtw_kernel<<<blocks, 256, 0, stream>>>(s, (unsigned short*)d, (int)n);
    };
    cvt(emb, w_emb, (size_t)4096 * 512);
    cvtpad_kernel<<<512, 256, 0, stream>>>(se_w1, w_se1p, 515);
    cvtpad_kernel<<<512, 256, 0, stream>>>(be_w1, w_be1p, 517);
    cvt(se_w2, w_se2, (size_t)512 * 512);
    cvt(be_w2, w_be2, (size_t)512 * 512);
    cvt(sa_in_w, w_sain, (size_t)4 * 1536 * 512);
    cvt(sa_out_w, w_saout, (size_t)4 * 512 * 512);
    cvt(ca_in_w, w_cain, (size_t)4 * 1536 * 512);
    cvt(ca_out_w, w_caout, (size_t)4 * 512 * 512);
    cvt(ff_w1, w_ff1, (size_t)4 * 2048 * 512);
    cvt(ff_w2, w_ff2, (size_t)4 * 2048 * 512);
    cvt(proj_w, w_proj, (size_t)4096 * 512);

    auto launch_mfma = [&](const bf16* A, const bf16* W, const float* bias,
                           void* C, int c_bf16, int M, int N, int K, int relu, int smode) {
        dim3 g(N / 128, (M + 127) / 128);
        mfma_gemm<<<g, 256, 0, stream>>>(A, W, bias, C, M, N, K, c_bf16, relu, smode);
    };

    // ---------------- setup: encoders, env ----------------
    {
        uintptr_t sp = big;
        auto salloc = [&](size_t b) -> char* { char* r = (char*)sp; sp += ALIGN(b); return r; };
        bf16*  xcat_b = (bf16*) salloc((size_t)1024 * 576 * 2);
        bf16*  h1b    = (bf16*) salloc((size_t)1024 * 512 * 2);
        float* fused  = (float*)salloc((size_t)1024 * 512 * 4);
        bf16*  acat_b = (bf16*) salloc((size_t)8192 * 576 * 2);
        bf16*  ah1b   = (bf16*) salloc((size_t)8192 * 512 * 2);
        float* astate = (float*)salloc((size_t)8192 * 512 * 4);

        xcatb_kernel<<<1024, 128, 0, stream>>>(input_ids, ego, w_emb, xcat_b);
        launch_mfma(xcat_b, w_se1p, se_b1, h1b, 1, 1024, 512, 576, 1, 0);
        launch_mfma(h1b, w_se2, se_b2, fused, 0, 1024, 512, 512, 0, 0);
        ln_kernel<<<256, 256, 0, stream>>>(fused, in_g, in_b, ss_b, 1024);

        acatb_kernel<<<8192, 128, 0, stream>>>(atok, afeat, w_emb, acat_b);
        launch_mfma(acat_b, w_be1p, be_b1, ah1b, 1, 8192, 512, 576, 1, 0);
        launch_mfma(ah1b, w_be2, be_b2, astate, 0, 8192, 512, 512, 0, 0);
        env_ln_kernel<<<2304, 256, 0, stream>>>(astate, atok, emb, goal, mem_g, mem_b, env_b);
    }

    // ---------------- layer-0 shared prefix ----------------
    launch_mfma(ss_b, w_sain, sa_in_b, qkv0, 1, 1024, 1536, 512, 0, 0);
    self_attn_mfma<<<32 * 4, 256, 0, stream>>>(qkv0, input_ids, araw0);
    launch_mfma(araw0, w_saout, sa_out_b, brnch0, 1, 1024, 512, 512, 0, 0);
    ln_res2_kernel<<<256, 256, 0, stream>>>(ss_b, 0x7fffffff, brnch0,
                                            ln1_g, ln1_b, xb0, 1024);
    launch_mfma(xb0, w_cain, ca_in_b, q0b, 1, 1024, 512, 512, 0, 0);

    // ---------------- decode ----------------
    {
        uintptr_t sp = big;
        auto salloc = [&](size_t b) -> char* { char* r = (char*)sp; sp += ALIGN(b); return r; };
        bf16* xb    = (bf16*)salloc((size_t)CH * 1024 * 512 * 2);
        bf16* uni   = (bf16*)salloc((size_t)CH * 1024 * 2048 * 2);  // qkv / q / ff1b
        bf16* araw  = (bf16*)salloc((size_t)CH * 1024 * 512 * 2);
        bf16* brnch = (bf16*)salloc((size_t)CH * 1024 * 512 * 2);

        auto env_kv_for = [&](int l) {
            launch_mfma(env_b, w_cain + (size_t)l * 1536 * 512 + (size_t)512 * 512,
                        ca_in_b + l * 1536 + 512, env_kv1, 1, 9216, 1024, 512, 0, 0);
        };

        for (int m0 = 0; m0 < 31; m0 += CH) {
            int cm = (31 - m0) < CH ? (31 - m0) : CH;
            int Mr = cm * 1024;
            // --- layer 0 (shared self-attn prefix + shared q precomputed) ---
            env_kv_for(0);
            cross_attn_mfma<<<cm * 32 * 4, 256, 0, stream>>>(q0b, 1, env_kv1, araw, m0);
            launch_mfma(araw, w_caout, ca_out_b, brnch, 1, Mr, 512, 512, 0, 0);
            ln_res2_kernel<<<(Mr + 3) / 4, 256, 0, stream>>>(xb0, 1023, brnch,
                                                             ln2_g, ln2_b, xb, Mr);
            launch_mfma(xb, w_ff1, ff_b1, uni, 1, Mr, 2048, 512, 1, 0);
            launch_mfma(uni, w_ff2, ff_b2, brnch, 1, Mr, 512, 2048, 0, 0);
            ln_res2_kernel<<<(Mr + 3) / 4, 256, 0, stream>>>(xb, 0x7fffffff, brnch,
                                                             ln3_g, ln3_b, xb, Mr);
            // --- layers 1..3 ---
            for (int l = 1; l < 4; ++l) {
                launch_mfma(xb, w_sain + (size_t)l * 1536 * 512, sa_in_b + l * 1536,
                            uni, 1, Mr, 1536, 512, 0, 0);
                self_attn_mfma<<<cm * 32 * 4, 256, 0, stream>>>(uni, input_ids, araw);
                launch_mfma(araw, w_saout + (size_t)l * 512 * 512, sa_out_b + l * 512,
                            brnch, 1, Mr, 512, 512, 0, 0);
                ln_res2_kernel<<<(Mr + 3) / 4, 256, 0, stream>>>(xb, 0x7fffffff, brnch,
                                                                 ln1_g + l * 512, ln1_b + l * 512, xb, Mr);
                launch_mfma(xb, w_cain + (size_t)l * 1536 * 512, ca_in_b + l * 1536,
                            uni, 1, Mr, 512, 512, 0, 0);
                env_kv_for(l);
                cross_attn_mfma<<<cm * 32 * 4, 256, 0, stream>>>(uni, 0, env_kv1, araw, m0);
                launch_mfma(araw, w_caout + (size_t)l * 512 * 512, ca_out_b + l * 512,
                            brnch, 1, Mr, 512, 512, 0, 0);
                ln_res2_kernel<<<(Mr + 3) / 4, 256, 0, stream>>>(xb, 0x7fffffff, brnch,
                                                                 ln2_g + l * 512, ln2_b + l * 512, xb, Mr);
                launch_mfma(xb, w_ff1 + (size_t)l * 2048 * 512, ff_b1 + l * 2048,
                            uni, 1, Mr, 2048, 512, 1, 0);
                launch_mfma(uni, w_ff2 + (size_t)l * 512 * 2048, ff_b2 + l * 512,
                            brnch, 1, Mr, 512, 2048, 0, 0);
                ln_res2_kernel<<<(Mr + 3) / 4, 256, 0, stream>>>(xb, 0x7fffffff, brnch,
                                                                 ln3_g + l * 512, ln3_b + l * 512, xb, Mr);
            }
            sel_kernel<<<cm * 32, 128, 0, stream>>>(xb, sel_b, m0, cm);
        }
    }

    // ---------------- final: LN + vocab projection (transposed store) ----------------
    ln_res2_kernel<<<248, 256, 0, stream>>>(sel_b, 0x7fffffff, (const bf16*)nullptr,
                                            outn_g, outn_b, sel_ln_b, 992);
    launch_mfma(sel_ln_b, w_proj, proj_b, out, 0, 992, 4096, 512, 0, 1);
}